// Round 2
// baseline (434.856 us; speedup 1.0000x reference)
//
#include <hip/hip_runtime.h>
#include <hip/hip_bf16.h>
#include <stdint.h>

// SumThenRegRpeSelfAttention: B=4 T=1024 E=768 H=12 DH=64 P=65
// Pipeline: cast -> [stage1 GEMM qkv x6] -> sum-attn -> [k2v2 GEMM] -> reg-attn(+RPE) -> [out GEMM]

#define DEV __device__ __forceinline__

using f32x4 = __attribute__((ext_vector_type(4))) float;
using s16x8 = __attribute__((ext_vector_type(8))) short;
using s16x4 = __attribute__((ext_vector_type(4))) short;
using i32x4 = __attribute__((ext_vector_type(4))) int;
using fvec4 = __attribute__((ext_vector_type(4))) float;
using u16 = unsigned short;

static constexpr int KD = 768;            // inner K of every GEMM
static constexpr int PE = 4096 * 768;     // elems per projection tensor

DEV u16 f2bf(float f) {
  uint32_t u = __builtin_bit_cast(uint32_t, f);
  u += 0x7FFF + ((u >> 16) & 1);
  return (u16)(u >> 16);
}
DEV float bf2f(u16 h) { return __builtin_bit_cast(float, (uint32_t)h << 16); }

DEV void gload16(const void* g, void* l) {
  __builtin_amdgcn_global_load_lds((const __attribute__((address_space(1))) void*)g,
                                   (__attribute__((address_space(3))) void*)l, 16, 0, 0);
}
DEV f32x4 mfma16(s16x8 a, s16x8 b, f32x4 c) {
  return __builtin_amdgcn_mfma_f32_16x16x32_bf16(a, b, c, 0, 0, 0);
}

// ---------------- cast f32 -> bf16 (14 jobs) ----------------
struct CastJobs {
  const float* src[14];
  u16* dst[14];
  int n[14];
};
__global__ __launch_bounds__(256) void cast_bf16_kernel(CastJobs J) {
  const int job = blockIdx.y;
  const int i = (blockIdx.x * 256 + threadIdx.x) * 8;
  if (i >= J.n[job]) return;
  const fvec4* s = (const fvec4*)(J.src[job] + i);
  fvec4 a = s[0], b = s[1];
  s16x8 o;
  o[0] = (short)f2bf(a[0]); o[1] = (short)f2bf(a[1]);
  o[2] = (short)f2bf(a[2]); o[3] = (short)f2bf(a[3]);
  o[4] = (short)f2bf(b[0]); o[5] = (short)f2bf(b[1]);
  o[6] = (short)f2bf(b[2]); o[7] = (short)f2bf(b[3]);
  *(s16x8*)(J.dst[job] + i) = o;
}

// ---------------- pack rel_pos0|rel_pos1 into u8 pairs ----------------
__global__ __launch_bounds__(256) void pack_rp_kernel(const int* rp0, const int* rp1, u16* outp) {
  const int i = (blockIdx.x * 256 + threadIdx.x) * 8;
  i32x4 a0 = *(const i32x4*)(rp0 + i), a1 = *(const i32x4*)(rp0 + i + 4);
  i32x4 b0 = *(const i32x4*)(rp1 + i), b1 = *(const i32x4*)(rp1 + i + 4);
  s16x8 o;
  o[0] = (short)(a0[0] | (b0[0] << 8));
  o[1] = (short)(a0[1] | (b0[1] << 8));
  o[2] = (short)(a0[2] | (b0[2] << 8));
  o[3] = (short)(a0[3] | (b0[3] << 8));
  o[4] = (short)(a1[0] | (b1[0] << 8));
  o[5] = (short)(a1[1] | (b1[1] << 8));
  o[6] = (short)(a1[2] | (b1[2] << 8));
  o[7] = (short)(a1[3] | (b1[3] << 8));
  *(s16x8*)(outp + i) = o;
}

// ---------------- generic GEMM: C = A(bf16, MxK) * W(bf16, NxK)^T ----------------
// epi: 0=stage1 (6 projections, head-major, V transposed), 1=k2v2, 2=rel table, 3=final f32
struct GemmP {
  const u16* A;
  const u16* Bw;
  const float* bias[6];
  u16* out_bf;
  float* out_f;
  int epi;
};

__global__ __launch_bounds__(256) void gemm_bt(GemmP p) {
  __shared__ __align__(16) u16 As[128 * 64];
  __shared__ __align__(16) u16 Bs[128 * 64];
  const int tid = threadIdx.x;
  const int m0 = blockIdx.x * 128, n0 = blockIdx.y * 128;
  const u16* Ag = p.A + (size_t)m0 * KD;
  const u16* Bg = p.Bw + (size_t)n0 * KD;
  const int lane = tid & 63, wid = tid >> 6;
  const int wm = (wid >> 1) * 64, wn = (wid & 1) * 64;
  const int lhi = lane >> 4, llo = lane & 15;

  uint ldso[4], srco[4];
#pragma unroll
  for (int j = 0; j < 4; ++j) {
    uint o = tid * 16 + j * 4096;
    uint row = o >> 7, kc = (o >> 4) & 7;
    ldso[j] = o;
    srco[j] = row * KD + ((kc ^ (row & 7)) << 3);
  }

  f32x4 acc[4][4] = {};

  for (int kt = 0; kt < 12; ++kt) {
    const int k0 = kt * 64;
#pragma unroll
    for (int j = 0; j < 4; ++j) gload16(Ag + srco[j] + k0, (char*)As + ldso[j]);
#pragma unroll
    for (int j = 0; j < 4; ++j) gload16(Bg + srco[j] + k0, (char*)Bs + ldso[j]);
    __syncthreads();
#pragma unroll
    for (int kf = 0; kf < 2; ++kf) {
      s16x8 av[4], bv[4];
#pragma unroll
      for (int mf = 0; mf < 4; ++mf) {
        int r = wm + mf * 16 + llo;
        av[mf] = *(const s16x8*)&As[r * 64 + ((((kf << 2) | lhi) ^ (r & 7)) << 3)];
      }
#pragma unroll
      for (int nf = 0; nf < 4; ++nf) {
        int r = wn + nf * 16 + llo;
        bv[nf] = *(const s16x8*)&Bs[r * 64 + ((((kf << 2) | lhi) ^ (r & 7)) << 3)];
      }
#pragma unroll
      for (int mf = 0; mf < 4; ++mf)
#pragma unroll
        for (int nf = 0; nf < 4; ++nf)
          acc[mf][nf] = mfma16(av[mf], bv[nf], acc[mf][nf]);
    }
    __syncthreads();
  }

  const int epi = p.epi;
#pragma unroll
  for (int nf = 0; nf < 4; ++nf) {
    const int n = n0 + wn + nf * 16 + llo;
    int proj = 0, n1 = n, hh, dd;
    float bias, scale = 1.0f;
    if (epi <= 1) {
      proj = n / 768; n1 = n - proj * 768;
      hh = n1 >> 6; dd = n1 & 63;
      bias = p.bias[proj][n1];
      if (epi == 0 && (proj == 0 || proj == 3)) scale = 0.125f;
    } else {
      hh = n >> 6; dd = n & 63;
      bias = p.bias[0][n];
    }
#pragma unroll
    for (int mf = 0; mf < 4; ++mf) {
      f32x4 c = acc[mf][nf];
      const int mb = m0 + wm + mf * 16 + lhi * 4;
      if (epi == 3) {
#pragma unroll
        for (int r = 0; r < 4; ++r)
          p.out_f[(size_t)(mb + r) * 768 + n] = c[r] + bias;
      } else if (epi == 2) {
#pragma unroll
        for (int r = 0; r < 4; ++r) {
          int m = mb + r;
          if (m < 80) p.out_bf[((size_t)hh * 80 + m) * 64 + dd] = f2bf(c[r] + bias);
        }
      } else {
        const bool vlay = (epi == 0) ? (proj == 2 || proj == 5) : (proj == 1);
        if (vlay) {
          const int b = mb >> 10, t = mb & 1023;
          const int bh = b * 12 + hh;
          s16x4 o4;
          o4[0] = (short)f2bf((c[0] + bias) * scale);
          o4[1] = (short)f2bf((c[1] + bias) * scale);
          o4[2] = (short)f2bf((c[2] + bias) * scale);
          o4[3] = (short)f2bf((c[3] + bias) * scale);
          *(s16x4*)&p.out_bf[(size_t)proj * PE + ((size_t)(bh * 64 + dd)) * 1024 + t] = o4;
        } else {
#pragma unroll
          for (int r = 0; r < 4; ++r) {
            int m = mb + r;
            int b = m >> 10, t = m & 1023;
            int bh = b * 12 + hh;
            p.out_bf[(size_t)proj * PE + ((size_t)(bh * 1024 + t)) * 64 + dd] =
                f2bf((c[r] + bias) * scale);
          }
        }
      }
    }
  }
}

// ---------------- sum-branch flash attention ----------------
// grid (qt=16, bh=48), 256 thr, QB=64 (16 q-rows per wave), KB=64
__global__ __launch_bounds__(256) void sum_attn_kernel(const u16* Qs, const u16* Ks,
                                                       const u16* Vst, u16* sum_x) {
  __shared__ __align__(16) u16 kbuf[64 * 64];
  __shared__ __align__(16) u16 vbuf[64 * 64];
  __shared__ __align__(16) u16 pbuf[4][16 * 72];
  const int tid = threadIdx.x, lane = tid & 63, w = tid >> 6;
  const int lhi = lane >> 4, llo = lane & 15;
  const int qt = blockIdx.x, bh = blockIdx.y;
  const int qbase = qt * 64 + w * 16;

  const u16* Qg = Qs + ((size_t)bh * 1024 + qbase + llo) * 64;
  s16x8 aq0 = *(const s16x8*)(Qg + lhi * 8);
  s16x8 aq1 = *(const s16x8*)(Qg + 32 + lhi * 8);

  f32x4 accO[4] = {};
  float mrun[4], lrun[4];
#pragma unroll
  for (int r = 0; r < 4; ++r) { mrun[r] = -1e30f; lrun[r] = 0.f; }

  uint so[2], srow[2], sswz[2];
#pragma unroll
  for (int j = 0; j < 2; ++j) {
    uint o = tid * 16 + j * 4096;
    so[j] = o; srow[j] = o >> 7;
    sswz[j] = (((o >> 4) & 7) ^ (srow[j] & 7)) << 3;
  }
  const u16* Kg = Ks + (size_t)bh * 65536;
  const u16* Vg = Vst + (size_t)bh * 65536;

  for (int kt = 0; kt < 16; ++kt) {
#pragma unroll
    for (int j = 0; j < 2; ++j) {
      gload16(Kg + (size_t)kt * 4096 + srow[j] * 64 + sswz[j], (char*)kbuf + so[j]);
      gload16(Vg + (size_t)srow[j] * 1024 + kt * 64 + sswz[j], (char*)vbuf + so[j]);
    }
    __syncthreads();

    f32x4 s[4];
#pragma unroll
    for (int kc4 = 0; kc4 < 4; ++kc4) {
      f32x4 c = {};
#pragma unroll
      for (int kf = 0; kf < 2; ++kf) {
        int kr = kc4 * 16 + llo;
        s16x8 bk = *(const s16x8*)&kbuf[kr * 64 + ((((kf << 2) | lhi) ^ (kr & 7)) << 3)];
        c = mfma16(kf ? aq1 : aq0, bk, c);
      }
      s[kc4] = c;
    }

    float pmax[4], corr[4], lpart[4];
#pragma unroll
    for (int r = 0; r < 4; ++r)
      pmax[r] = fmaxf(fmaxf(s[0][r], s[1][r]), fmaxf(s[2][r], s[3][r]));
#pragma unroll
    for (int msk = 1; msk < 16; msk <<= 1)
#pragma unroll
      for (int r = 0; r < 4; ++r)
        pmax[r] = fmaxf(pmax[r], __shfl_xor(pmax[r], msk, 64));
#pragma unroll
    for (int r = 0; r < 4; ++r) {
      float mn = fmaxf(mrun[r], pmax[r]);
      corr[r] = __expf(mrun[r] - mn);
      mrun[r] = mn; lpart[r] = 0.f;
    }
#pragma unroll
    for (int kc4 = 0; kc4 < 4; ++kc4)
#pragma unroll
      for (int r = 0; r < 4; ++r) {
        float pv = __expf(s[kc4][r] - mrun[r]);
        lpart[r] += pv;
        pbuf[w][(lhi * 4 + r) * 72 + kc4 * 16 + llo] = f2bf(pv);
      }
#pragma unroll
    for (int msk = 1; msk < 16; msk <<= 1)
#pragma unroll
      for (int r = 0; r < 4; ++r)
        lpart[r] += __shfl_xor(lpart[r], msk, 64);
#pragma unroll
    for (int r = 0; r < 4; ++r) lrun[r] = lrun[r] * corr[r] + lpart[r];
#pragma unroll
    for (int dc = 0; dc < 4; ++dc)
#pragma unroll
      for (int r = 0; r < 4; ++r) accO[dc][r] *= corr[r];

    asm volatile("s_waitcnt lgkmcnt(0)" ::: "memory");
    __builtin_amdgcn_sched_barrier(0);

#pragma unroll
    for (int kf = 0; kf < 2; ++kf) {
      s16x8 ap = *(const s16x8*)&pbuf[w][llo * 72 + kf * 32 + lhi * 8];
#pragma unroll
      for (int dc = 0; dc < 4; ++dc) {
        int dr = dc * 16 + llo;
        s16x8 bv = *(const s16x8*)&vbuf[dr * 64 + ((((kf << 2) | lhi) ^ (dr & 7)) << 3)];
        accO[dc] = mfma16(ap, bv, accO[dc]);
      }
    }
    __syncthreads();
  }

  const int b = bh / 12, hh = bh - b * 12;
#pragma unroll
  for (int dc = 0; dc < 4; ++dc)
#pragma unroll
    for (int r = 0; r < 4; ++r) {
      int q = qbase + lhi * 4 + r;
      float o = accO[dc][r] / lrun[r];
      sum_x[((size_t)b * 1024 + q) * 768 + hh * 64 + dc * 16 + llo] = f2bf(o);
    }
}

// ---------------- reg-branch flash attention with RPE gather ----------------
__global__ __launch_bounds__(256) void reg_attn_kernel(
    const u16* Qr, const u16* Kr, const u16* Vrt,
    const u16* K2, const u16* V2t,
    const u16* tab0, const u16* tab1,
    const u16* rpk, u16* attn_out) {
  __shared__ __align__(16) u16 kbuf[64 * 64];
  __shared__ __align__(16) u16 vbuf[64 * 64];
  __shared__ __align__(16) u16 tsb[2][64 * 80];
  __shared__ __align__(16) u16 pbuf[4][16 * 72];
  const int tid = threadIdx.x, lane = tid & 63, w = tid >> 6;
  const int lhi = lane >> 4, llo = lane & 15;
  const int qt = blockIdx.x, bh = blockIdx.y;
  const int b = bh / 12, hh = bh - b * 12;
  const int qbase = qt * 64 + w * 16;

  const u16* Qg = Qr + ((size_t)bh * 1024 + qbase + llo) * 64;
  s16x8 aq0 = *(const s16x8*)(Qg + lhi * 8);
  s16x8 aq1 = *(const s16x8*)(Qg + 32 + lhi * 8);

  // ts = Q @ table^T  (per-wave rows), kept in LDS as bf16
#pragma unroll
  for (int tt = 0; tt < 2; ++tt) {
    const u16* tb = tt ? tab1 : tab0;
#pragma unroll
    for (int pf = 0; pf < 5; ++pf) {
      f32x4 c = {};
#pragma unroll
      for (int kf = 0; kf < 2; ++kf) {
        s16x8 bt = *(const s16x8*)(tb + ((size_t)hh * 80 + pf * 16 + llo) * 64 + kf * 32 + lhi * 8);
        c = mfma16(kf ? aq1 : aq0, bt, c);
      }
#pragma unroll
      for (int r = 0; r < 4; ++r)
        tsb[tt][(w * 16 + lhi * 4 + r) * 80 + pf * 16 + llo] = f2bf(c[r]);
    }
  }
  __syncthreads();

  f32x4 accO[4] = {};
  float mrun[4], lrun[4];
#pragma unroll
  for (int r = 0; r < 4; ++r) { mrun[r] = -1e30f; lrun[r] = 0.f; }

  uint so[2], srow[2], sswz[2];
#pragma unroll
  for (int j = 0; j < 2; ++j) {
    uint o = tid * 16 + j * 4096;
    so[j] = o; srow[j] = o >> 7;
    sswz[j] = (((o >> 4) & 7) ^ (srow[j] & 7)) << 3;
  }
  const u16* KgA = Kr + (size_t)bh * 65536;
  const u16* KgB = K2 + (size_t)bh * 65536;
  const u16* VgA = Vrt + (size_t)bh * 65536;
  const u16* VgB = V2t + (size_t)bh * 65536;

  for (int kt = 0; kt < 32; ++kt) {
    const bool ph1 = kt < 16;
    const int kk = ph1 ? kt : kt - 16;
    const u16* Kg = ph1 ? KgA : KgB;
    const u16* Vg = ph1 ? VgA : VgB;
#pragma unroll
    for (int j = 0; j < 2; ++j) {
      gload16(Kg + (size_t)kk * 4096 + srow[j] * 64 + sswz[j], (char*)kbuf + so[j]);
      gload16(Vg + (size_t)srow[j] * 1024 + kk * 64 + sswz[j], (char*)vbuf + so[j]);
    }
    __syncthreads();

    f32x4 s[4];
#pragma unroll
    for (int kc4 = 0; kc4 < 4; ++kc4) {
      f32x4 c = {};
#pragma unroll
      for (int kf = 0; kf < 2; ++kf) {
        int kr = kc4 * 16 + llo;
        s16x8 bk = *(const s16x8*)&kbuf[kr * 64 + ((((kf << 2) | lhi) ^ (kr & 7)) << 3)];
        c = mfma16(kf ? aq1 : aq0, bk, c);
      }
      s[kc4] = c;
    }

    if (ph1) {  // RPE bias gather (reg keys only)
      u16 pp[16];
#pragma unroll
      for (int kc4 = 0; kc4 < 4; ++kc4)
#pragma unroll
        for (int r = 0; r < 4; ++r)
          pp[kc4 * 4 + r] =
              rpk[(size_t)(qbase + lhi * 4 + r) * 1024 + kt * 64 + kc4 * 16 + llo];
#pragma unroll
      for (int kc4 = 0; kc4 < 4; ++kc4)
#pragma unroll
        for (int r = 0; r < 4; ++r) {
          u16 v = pp[kc4 * 4 + r];
          int ql = w * 16 + lhi * 4 + r;
          s[kc4][r] += bf2f(tsb[0][ql * 80 + (v & 255)]) + bf2f(tsb[1][ql * 80 + (v >> 8)]);
        }
    }

    float pmax[4], corr[4], lpart[4];
#pragma unroll
    for (int r = 0; r < 4; ++r)
      pmax[r] = fmaxf(fmaxf(s[0][r], s[1][r]), fmaxf(s[2][r], s[3][r]));
#pragma unroll
    for (int msk = 1; msk < 16; msk <<= 1)
#pragma unroll
      for (int r = 0; r < 4; ++r)
        pmax[r] = fmaxf(pmax[r], __shfl_xor(pmax[r], msk, 64));
#pragma unroll
    for (int r = 0; r < 4; ++r) {
      float mn = fmaxf(mrun[r], pmax[r]);
      corr[r] = __expf(mrun[r] - mn);
      mrun[r] = mn; lpart[r] = 0.f;
    }
#pragma unroll
    for (int kc4 = 0; kc4 < 4; ++kc4)
#pragma unroll
      for (int r = 0; r < 4; ++r) {
        float pv = __expf(s[kc4][r] - mrun[r]);
        lpart[r] += pv;
        pbuf[w][(lhi * 4 + r) * 72 + kc4 * 16 + llo] = f2bf(pv);
      }
#pragma unroll
    for (int msk = 1; msk < 16; msk <<= 1)
#pragma unroll
      for (int r = 0; r < 4; ++r)
        lpart[r] += __shfl_xor(lpart[r], msk, 64);
#pragma unroll
    for (int r = 0; r < 4; ++r) lrun[r] = lrun[r] * corr[r] + lpart[r];
#pragma unroll
    for (int dc = 0; dc < 4; ++dc)
#pragma unroll
      for (int r = 0; r < 4; ++r) accO[dc][r] *= corr[r];

    asm volatile("s_waitcnt lgkmcnt(0)" ::: "memory");
    __builtin_amdgcn_sched_barrier(0);

#pragma unroll
    for (int kf = 0; kf < 2; ++kf) {
      s16x8 ap = *(const s16x8*)&pbuf[w][llo * 72 + kf * 32 + lhi * 8];
#pragma unroll
      for (int dc = 0; dc < 4; ++dc) {
        int dr = dc * 16 + llo;
        s16x8 bv = *(const s16x8*)&vbuf[dr * 64 + ((((kf << 2) | lhi) ^ (dr & 7)) << 3)];
        accO[dc] = mfma16(ap, bv, accO[dc]);
      }
    }
    __syncthreads();
  }

#pragma unroll
  for (int dc = 0; dc < 4; ++dc)
#pragma unroll
    for (int r = 0; r < 4; ++r) {
      int q = qbase + lhi * 4 + r;
      float o = accO[dc][r] / lrun[r];
      attn_out[((size_t)b * 1024 + q) * 768 + hh * 64 + dc * 16 + llo] = f2bf(o);
    }
}

// ---------------- launch ----------------
extern "C" void kernel_launch(void* const* d_in, const int* in_sizes, int n_in,
                              void* d_out, int out_size, void* d_ws, size_t ws_size,
                              hipStream_t stream) {
  (void)in_sizes; (void)n_in; (void)out_size; (void)ws_size;
  const float* x     = (const float*)d_in[0];
  const int*   rp0   = (const int*)d_in[1];
  const int*   rp1   = (const int*)d_in[2];
  const float* re0   = (const float*)d_in[3];
  const float* re1   = (const float*)d_in[4];
  const float* Wq_r  = (const float*)d_in[5];  const float* bq_r = (const float*)d_in[6];
  const float* Wk_r  = (const float*)d_in[7];  const float* bk_r = (const float*)d_in[8];
  const float* Wv_r  = (const float*)d_in[9];  const float* bv_r = (const float*)d_in[10];
  const float* Wq_s  = (const float*)d_in[11]; const float* bq_s = (const float*)d_in[12];
  const float* Wk_s  = (const float*)d_in[13]; const float* bk_s = (const float*)d_in[14];
  const float* Wv_s  = (const float*)d_in[15]; const float* bv_s = (const float*)d_in[16];
  const float* Wk2   = (const float*)d_in[17]; const float* bk2  = (const float*)d_in[18];
  const float* Wv2   = (const float*)d_in[19]; const float* bv2  = (const float*)d_in[20];
  const float* Wrel0 = (const float*)d_in[21]; const float* brel0 = (const float*)d_in[22];
  const float* Wrel1 = (const float*)d_in[23]; const float* brel1 = (const float*)d_in[24];
  const float* Wo    = (const float*)d_in[25]; const float* bo   = (const float*)d_in[26];
  float* out = (float*)d_out;

  char* wp = (char*)d_ws;
  auto carve = [&](size_t bytes) {
    char* r = wp;
    wp += (bytes + 255) & ~(size_t)255;
    return r;
  };
  u16* xb     = (u16*)carve((size_t)PE * 2);
  u16* Wcat1  = (u16*)carve((size_t)4608 * 768 * 2);
  u16* Wcat2  = (u16*)carve((size_t)1536 * 768 * 2);
  u16* Wrel0b = (u16*)carve((size_t)768 * 768 * 2);
  u16* Wrel1b = (u16*)carve((size_t)768 * 768 * 2);
  u16* Wob    = (u16*)carve((size_t)768 * 768 * 2);
  u16* relA0  = (u16*)carve((size_t)128 * 768 * 2);
  u16* relA1  = (u16*)carve((size_t)128 * 768 * 2);
  u16* qkv    = (u16*)carve((size_t)6 * PE * 2);   // Qr,Kr,Vrt,Qs,Ks,Vst
  u16* k2v2   = (u16*)carve((size_t)2 * PE * 2);   // K2, V2t
  u16* tb0    = (u16*)carve((size_t)12 * 80 * 64 * 2);
  u16* tb1    = (u16*)carve((size_t)12 * 80 * 64 * 2);
  u16* rpk    = (u16*)carve((size_t)1024 * 1024 * 2);
  u16* sumx   = (u16*)carve((size_t)PE * 2);
  u16* aout   = (u16*)carve((size_t)PE * 2);

  const int wn_ = 768 * 768;
  CastJobs J;
  const float* srcs[14] = {x, Wq_r, Wk_r, Wv_r, Wq_s, Wk_s, Wv_s, Wk2, Wv2, Wrel0, Wrel1, Wo, re0, re1};
  u16* dsts[14] = {xb, Wcat1, Wcat1 + wn_, Wcat1 + 2 * wn_, Wcat1 + 3 * wn_, Wcat1 + 4 * wn_,
                   Wcat1 + 5 * wn_, Wcat2, Wcat2 + wn_, Wrel0b, Wrel1b, Wob, relA0, relA1};
  int ns[14] = {PE, wn_, wn_, wn_, wn_, wn_, wn_, wn_, wn_, wn_, wn_, wn_, 65 * 768, 65 * 768};
  for (int i = 0; i < 14; ++i) { J.src[i] = srcs[i]; J.dst[i] = dsts[i]; J.n[i] = ns[i]; }
  cast_bf16_kernel<<<dim3(1536, 14), 256, 0, stream>>>(J);

  pack_rp_kernel<<<dim3(512), 256, 0, stream>>>(rp0, rp1, rpk);

  GemmP g1{};
  g1.A = xb; g1.Bw = Wcat1;
  g1.bias[0] = bq_r; g1.bias[1] = bk_r; g1.bias[2] = bv_r;
  g1.bias[3] = bq_s; g1.bias[4] = bk_s; g1.bias[5] = bv_s;
  g1.out_bf = qkv; g1.epi = 0;
  gemm_bt<<<dim3(32, 36), 256, 0, stream>>>(g1);

  GemmP gt0{}; gt0.A = relA0; gt0.Bw = Wrel0b; gt0.bias[0] = brel0; gt0.out_bf = tb0; gt0.epi = 2;
  gemm_bt<<<dim3(1, 6), 256, 0, stream>>>(gt0);
  GemmP gt1{}; gt1.A = relA1; gt1.Bw = Wrel1b; gt1.bias[0] = brel1; gt1.out_bf = tb1; gt1.epi = 2;
  gemm_bt<<<dim3(1, 6), 256, 0, stream>>>(gt1);

  sum_attn_kernel<<<dim3(16, 48), 256, 0, stream>>>(qkv + (size_t)3 * PE, qkv + (size_t)4 * PE,
                                                    qkv + (size_t)5 * PE, sumx);

  GemmP g2{};
  g2.A = sumx; g2.Bw = Wcat2; g2.bias[0] = bk2; g2.bias[1] = bv2;
  g2.out_bf = k2v2; g2.epi = 1;
  gemm_bt<<<dim3(32, 12), 256, 0, stream>>>(g2);

  reg_attn_kernel<<<dim3(16, 48), 256, 0, stream>>>(qkv, qkv + (size_t)PE, qkv + (size_t)2 * PE,
                                                    k2v2, k2v2 + (size_t)PE, tb0, tb1, rpk, aout);

  GemmP gf{};
  gf.A = aout; gf.Bw = Wob; gf.bias[0] = bo; gf.out_f = out; gf.epi = 3;
  gemm_bt<<<dim3(32, 6), 256, 0, stream>>>(gf);
}

// Round 3
// 386.515 us; speedup vs baseline: 1.1251x; 1.1251x over previous
//
#include <hip/hip_runtime.h>
#include <hip/hip_bf16.h>
#include <stdint.h>

// SumThenRegRpeSelfAttention: B=4 T=1024 E=768 H=12 DH=64 P=65
// Pipeline: cast -> [stage1 GEMM qkv x6] -> sum-attn -> [k2v2 GEMM] -> reg-attn(+RPE) -> [out GEMM]

#define DEV __device__ __forceinline__

using f32x4 = __attribute__((ext_vector_type(4))) float;
using s16x8 = __attribute__((ext_vector_type(8))) short;
using s16x4 = __attribute__((ext_vector_type(4))) short;
using i32x4 = __attribute__((ext_vector_type(4))) int;
using fvec4 = __attribute__((ext_vector_type(4))) float;
using u16 = unsigned short;

static constexpr int KD = 768;            // inner K of every GEMM
static constexpr int PE = 4096 * 768;     // elems per projection tensor

DEV u16 f2bf(float f) {
  uint32_t u = __builtin_bit_cast(uint32_t, f);
  u += 0x7FFF + ((u >> 16) & 1);
  return (u16)(u >> 16);
}
DEV float bf2f(u16 h) { return __builtin_bit_cast(float, (uint32_t)h << 16); }

DEV void gload16(const void* g, void* l) {
  __builtin_amdgcn_global_load_lds((const __attribute__((address_space(1))) void*)g,
                                   (__attribute__((address_space(3))) void*)l, 16, 0, 0);
}
DEV f32x4 mfma16(s16x8 a, s16x8 b, f32x4 c) {
  return __builtin_amdgcn_mfma_f32_16x16x32_bf16(a, b, c, 0, 0, 0);
}

// ---------------- cast f32 -> bf16 (14 jobs) ----------------
struct CastJobs {
  const float* src[14];
  u16* dst[14];
  int n[14];
};
__global__ __launch_bounds__(256) void cast_bf16_kernel(CastJobs J) {
  const int job = blockIdx.y;
  const int i = (blockIdx.x * 256 + threadIdx.x) * 8;
  if (i >= J.n[job]) return;
  const fvec4* s = (const fvec4*)(J.src[job] + i);
  fvec4 a = s[0], b = s[1];
  s16x8 o;
  o[0] = (short)f2bf(a[0]); o[1] = (short)f2bf(a[1]);
  o[2] = (short)f2bf(a[2]); o[3] = (short)f2bf(a[3]);
  o[4] = (short)f2bf(b[0]); o[5] = (short)f2bf(b[1]);
  o[6] = (short)f2bf(b[2]); o[7] = (short)f2bf(b[3]);
  *(s16x8*)(J.dst[job] + i) = o;
}

// ---------------- pack rel_pos0|rel_pos1 into u8 pairs ----------------
__global__ __launch_bounds__(256) void pack_rp_kernel(const int* rp0, const int* rp1, u16* outp) {
  const int i = (blockIdx.x * 256 + threadIdx.x) * 8;
  i32x4 a0 = *(const i32x4*)(rp0 + i), a1 = *(const i32x4*)(rp0 + i + 4);
  i32x4 b0 = *(const i32x4*)(rp1 + i), b1 = *(const i32x4*)(rp1 + i + 4);
  s16x8 o;
  o[0] = (short)(a0[0] | (b0[0] << 8));
  o[1] = (short)(a0[1] | (b0[1] << 8));
  o[2] = (short)(a0[2] | (b0[2] << 8));
  o[3] = (short)(a0[3] | (b0[3] << 8));
  o[4] = (short)(a1[0] | (b1[0] << 8));
  o[5] = (short)(a1[1] | (b1[1] << 8));
  o[6] = (short)(a1[2] | (b1[2] << 8));
  o[7] = (short)(a1[3] | (b1[3] << 8));
  *(s16x8*)(outp + i) = o;
}

// ---------------- generic GEMM: C = A(bf16, MxK) * W(bf16, NxK)^T ----------------
// epi: 0=stage1 (6 projections, head-major, V transposed), 1=k2v2, 2=rel table, 3=final f32
struct GemmP {
  const u16* A;
  const u16* Bw;
  const float* bias[6];
  u16* out_bf;
  float* out_f;
  int epi;
};

__global__ __launch_bounds__(256) void gemm_bt(GemmP p) {
  __shared__ __align__(16) u16 As[128 * 64];
  __shared__ __align__(16) u16 Bs[128 * 64];
  const int tid = threadIdx.x;
  const int m0 = blockIdx.x * 128, n0 = blockIdx.y * 128;
  const u16* Ag = p.A + (size_t)m0 * KD;
  const u16* Bg = p.Bw + (size_t)n0 * KD;
  const int lane = tid & 63, wid = tid >> 6;
  const int wm = (wid >> 1) * 64, wn = (wid & 1) * 64;
  const int lhi = lane >> 4, llo = lane & 15;

  uint ldso[4], srco[4];
#pragma unroll
  for (int j = 0; j < 4; ++j) {
    uint o = tid * 16 + j * 4096;
    uint row = o >> 7, kc = (o >> 4) & 7;
    ldso[j] = o;
    srco[j] = row * KD + ((kc ^ (row & 7)) << 3);
  }

  f32x4 acc[4][4] = {};

  for (int kt = 0; kt < 12; ++kt) {
    const int k0 = kt * 64;
#pragma unroll
    for (int j = 0; j < 4; ++j) gload16(Ag + srco[j] + k0, (char*)As + ldso[j]);
#pragma unroll
    for (int j = 0; j < 4; ++j) gload16(Bg + srco[j] + k0, (char*)Bs + ldso[j]);
    __syncthreads();
#pragma unroll
    for (int kf = 0; kf < 2; ++kf) {
      s16x8 av[4], bv[4];
#pragma unroll
      for (int mf = 0; mf < 4; ++mf) {
        int r = wm + mf * 16 + llo;
        av[mf] = *(const s16x8*)&As[r * 64 + ((((kf << 2) | lhi) ^ (r & 7)) << 3)];
      }
#pragma unroll
      for (int nf = 0; nf < 4; ++nf) {
        int r = wn + nf * 16 + llo;
        bv[nf] = *(const s16x8*)&Bs[r * 64 + ((((kf << 2) | lhi) ^ (r & 7)) << 3)];
      }
#pragma unroll
      for (int mf = 0; mf < 4; ++mf)
#pragma unroll
        for (int nf = 0; nf < 4; ++nf)
          acc[mf][nf] = mfma16(av[mf], bv[nf], acc[mf][nf]);
    }
    __syncthreads();
  }

  const int epi = p.epi;
#pragma unroll
  for (int nf = 0; nf < 4; ++nf) {
    const int n = n0 + wn + nf * 16 + llo;
    int proj = 0, n1 = n, hh, dd;
    float bias, scale = 1.0f;
    if (epi <= 1) {
      proj = n / 768; n1 = n - proj * 768;
      hh = n1 >> 6; dd = n1 & 63;
      bias = p.bias[proj][n1];
      if (epi == 0 && (proj == 0 || proj == 3)) scale = 0.125f;
    } else {
      hh = n >> 6; dd = n & 63;
      bias = p.bias[0][n];
    }
#pragma unroll
    for (int mf = 0; mf < 4; ++mf) {
      f32x4 c = acc[mf][nf];
      const int mb = m0 + wm + mf * 16 + lhi * 4;
      if (epi == 3) {
#pragma unroll
        for (int r = 0; r < 4; ++r)
          p.out_f[(size_t)(mb + r) * 768 + n] = c[r] + bias;
      } else if (epi == 2) {
#pragma unroll
        for (int r = 0; r < 4; ++r) {
          int m = mb + r;
          if (m < 80) p.out_bf[((size_t)hh * 80 + m) * 64 + dd] = f2bf(c[r] + bias);
        }
      } else {
        const bool vlay = (epi == 0) ? (proj == 2 || proj == 5) : (proj == 1);
        if (vlay) {
          const int b = mb >> 10, t = mb & 1023;
          const int bh = b * 12 + hh;
          s16x4 o4;
          o4[0] = (short)f2bf((c[0] + bias) * scale);
          o4[1] = (short)f2bf((c[1] + bias) * scale);
          o4[2] = (short)f2bf((c[2] + bias) * scale);
          o4[3] = (short)f2bf((c[3] + bias) * scale);
          *(s16x4*)&p.out_bf[(size_t)proj * PE + ((size_t)(bh * 64 + dd)) * 1024 + t] = o4;
        } else {
#pragma unroll
          for (int r = 0; r < 4; ++r) {
            int m = mb + r;
            int b = m >> 10, t = m & 1023;
            int bh = b * 12 + hh;
            p.out_bf[(size_t)proj * PE + ((size_t)(bh * 1024 + t)) * 64 + dd] =
                f2bf((c[r] + bias) * scale);
          }
        }
      }
    }
  }
}

// ---------------- sum-branch flash attention ----------------
// 1-D grid 768 (XCD-swizzled), 256 thr, QB=64 (16 q-rows per wave), KB=64
__global__ __launch_bounds__(256) void sum_attn_kernel(const u16* Qs, const u16* Ks,
                                                       const u16* Vst, u16* sum_x) {
  __shared__ __align__(16) u16 kbuf[64 * 64];
  __shared__ __align__(16) u16 vbuf[64 * 64];
  __shared__ __align__(16) u16 pbuf[4][16 * 72];
  const int tid = threadIdx.x, lane = tid & 63, w = tid >> 6;
  const int lhi = lane >> 4, llo = lane & 15;
  const int bid = blockIdx.x;
  const int vid = (bid & 7) * 96 + (bid >> 3);   // XCD-contiguous: 6 bh per XCD
  const int qt = vid & 15, bh = vid >> 4;
  const int qbase = qt * 64 + w * 16;

  const u16* Qg = Qs + ((size_t)bh * 1024 + qbase + llo) * 64;
  s16x8 aq0 = *(const s16x8*)(Qg + lhi * 8);
  s16x8 aq1 = *(const s16x8*)(Qg + 32 + lhi * 8);

  f32x4 accO[4] = {};
  float mrun[4], lrun[4];
#pragma unroll
  for (int r = 0; r < 4; ++r) { mrun[r] = -1e30f; lrun[r] = 0.f; }

  uint so[2], srow[2], sswz[2];
#pragma unroll
  for (int j = 0; j < 2; ++j) {
    uint o = tid * 16 + j * 4096;
    so[j] = o; srow[j] = o >> 7;
    sswz[j] = (((o >> 4) & 7) ^ (srow[j] & 7)) << 3;
  }
  const u16* Kg = Ks + (size_t)bh * 65536;
  const u16* Vg = Vst + (size_t)bh * 65536;

  for (int kt = 0; kt < 16; ++kt) {
#pragma unroll
    for (int j = 0; j < 2; ++j) {
      gload16(Kg + (size_t)kt * 4096 + srow[j] * 64 + sswz[j], (char*)kbuf + so[j]);
      gload16(Vg + (size_t)srow[j] * 1024 + kt * 64 + sswz[j], (char*)vbuf + so[j]);
    }
    __syncthreads();

    f32x4 s[4];
    __builtin_amdgcn_s_setprio(1);
#pragma unroll
    for (int kc4 = 0; kc4 < 4; ++kc4) {
      f32x4 c = {};
#pragma unroll
      for (int kf = 0; kf < 2; ++kf) {
        int kr = kc4 * 16 + llo;
        s16x8 bk = *(const s16x8*)&kbuf[kr * 64 + ((((kf << 2) | lhi) ^ (kr & 7)) << 3)];
        c = mfma16(kf ? aq1 : aq0, bk, c);
      }
      s[kc4] = c;
    }
    __builtin_amdgcn_s_setprio(0);

    // defer-max (T13): skip reduce+rescale when no lane's local max grew past THR=8
    float smx[4];
#pragma unroll
    for (int r = 0; r < 4; ++r)
      smx[r] = fmaxf(fmaxf(s[0][r], s[1][r]), fmaxf(s[2][r], s[3][r]));
    int ok = 1;
#pragma unroll
    for (int r = 0; r < 4; ++r) ok &= (smx[r] <= mrun[r] + 8.0f);
    if (!__all(ok)) {
#pragma unroll
      for (int msk = 1; msk < 16; msk <<= 1)
#pragma unroll
        for (int r = 0; r < 4; ++r)
          smx[r] = fmaxf(smx[r], __shfl_xor(smx[r], msk, 64));
#pragma unroll
      for (int r = 0; r < 4; ++r) {
        float mn = fmaxf(mrun[r], smx[r]);
        float corr = __expf(mrun[r] - mn);
        mrun[r] = mn;
        lrun[r] *= corr;
#pragma unroll
        for (int dc = 0; dc < 4; ++dc) accO[dc][r] *= corr;
      }
    }
    // P + per-lane partial l (reduced once at epilogue)
#pragma unroll
    for (int r = 0; r < 4; ++r) {
      float ls = 0.f;
#pragma unroll
      for (int kc4 = 0; kc4 < 4; ++kc4) {
        float pv = __expf(s[kc4][r] - mrun[r]);
        ls += pv;
        pbuf[w][(lhi * 4 + r) * 72 + kc4 * 16 + llo] = f2bf(pv);
      }
      lrun[r] += ls;
    }

    asm volatile("s_waitcnt lgkmcnt(0)" ::: "memory");
    __builtin_amdgcn_sched_barrier(0);

    __builtin_amdgcn_s_setprio(1);
#pragma unroll
    for (int kf = 0; kf < 2; ++kf) {
      s16x8 ap = *(const s16x8*)&pbuf[w][llo * 72 + kf * 32 + lhi * 8];
#pragma unroll
      for (int dc = 0; dc < 4; ++dc) {
        int dr = dc * 16 + llo;
        s16x8 bv = *(const s16x8*)&vbuf[dr * 64 + ((((kf << 2) | lhi) ^ (dr & 7)) << 3)];
        accO[dc] = mfma16(ap, bv, accO[dc]);
      }
    }
    __builtin_amdgcn_s_setprio(0);
    __syncthreads();
  }

  // epilogue l-reduction (moved out of the loop)
#pragma unroll
  for (int msk = 1; msk < 16; msk <<= 1)
#pragma unroll
    for (int r = 0; r < 4; ++r) lrun[r] += __shfl_xor(lrun[r], msk, 64);

  const int b = bh / 12, hh = bh - b * 12;
#pragma unroll
  for (int dc = 0; dc < 4; ++dc)
#pragma unroll
    for (int r = 0; r < 4; ++r) {
      int q = qbase + lhi * 4 + r;
      float o = accO[dc][r] / lrun[r];
      sum_x[((size_t)b * 1024 + q) * 768 + hh * 64 + dc * 16 + llo] = f2bf(o);
    }
}

// ---------------- reg-branch flash attention with RPE gather ----------------
__global__ __launch_bounds__(256) void reg_attn_kernel(
    const u16* Qr, const u16* Kr, const u16* Vrt,
    const u16* K2, const u16* V2t,
    const u16* tab0, const u16* tab1,
    const u16* rpk, u16* attn_out) {
  __shared__ __align__(16) u16 kbuf[64 * 64];
  __shared__ __align__(16) u16 vbuf[64 * 64];
  __shared__ __align__(16) u16 tsb[2][64 * 80];
  __shared__ __align__(16) u16 pbuf[4][16 * 72];
  const int tid = threadIdx.x, lane = tid & 63, w = tid >> 6;
  const int lhi = lane >> 4, llo = lane & 15;
  const int bid = blockIdx.x;
  const int vid = (bid & 7) * 96 + (bid >> 3);   // XCD-contiguous: 6 bh per XCD
  const int qt = vid & 15, bh = vid >> 4;
  const int b = bh / 12, hh = bh - b * 12;
  const int qbase = qt * 64 + w * 16;

  const u16* Qg = Qr + ((size_t)bh * 1024 + qbase + llo) * 64;
  s16x8 aq0 = *(const s16x8*)(Qg + lhi * 8);
  s16x8 aq1 = *(const s16x8*)(Qg + 32 + lhi * 8);

  // ts = Q @ table^T  (per-wave rows), kept in LDS as bf16
#pragma unroll
  for (int tt = 0; tt < 2; ++tt) {
    const u16* tb = tt ? tab1 : tab0;
#pragma unroll
    for (int pf = 0; pf < 5; ++pf) {
      f32x4 c = {};
#pragma unroll
      for (int kf = 0; kf < 2; ++kf) {
        s16x8 bt = *(const s16x8*)(tb + ((size_t)hh * 80 + pf * 16 + llo) * 64 + kf * 32 + lhi * 8);
        c = mfma16(kf ? aq1 : aq0, bt, c);
      }
#pragma unroll
      for (int r = 0; r < 4; ++r)
        tsb[tt][(w * 16 + lhi * 4 + r) * 80 + pf * 16 + llo] = f2bf(c[r]);
    }
  }
  __syncthreads();

  f32x4 accO[4] = {};
  float mrun[4], lrun[4];
#pragma unroll
  for (int r = 0; r < 4; ++r) { mrun[r] = -1e30f; lrun[r] = 0.f; }

  int tbase[4];
#pragma unroll
  for (int r = 0; r < 4; ++r) tbase[r] = (w * 16 + lhi * 4 + r) * 80;

  uint so[2], srow[2], sswz[2];
#pragma unroll
  for (int j = 0; j < 2; ++j) {
    uint o = tid * 16 + j * 4096;
    so[j] = o; srow[j] = o >> 7;
    sswz[j] = (((o >> 4) & 7) ^ (srow[j] & 7)) << 3;
  }
  const u16* KgA = Kr + (size_t)bh * 65536;
  const u16* KgB = K2 + (size_t)bh * 65536;
  const u16* VgA = Vrt + (size_t)bh * 65536;
  const u16* VgB = V2t + (size_t)bh * 65536;

  auto tile = [&](const u16* Kg, const u16* Vg, int kk, bool gather) {
    // stage K/V (async to LDS)
#pragma unroll
    for (int j = 0; j < 2; ++j) {
      gload16(Kg + (size_t)kk * 4096 + srow[j] * 64 + sswz[j], (char*)kbuf + so[j]);
      gload16(Vg + (size_t)srow[j] * 1024 + kk * 64 + sswz[j], (char*)vbuf + so[j]);
    }
    // prefetch gather indices BEFORE the barrier (latency hides under vmcnt drain)
    u16 pp[16];
    if (gather) {
#pragma unroll
      for (int kc4 = 0; kc4 < 4; ++kc4)
#pragma unroll
        for (int r = 0; r < 4; ++r)
          pp[kc4 * 4 + r] =
              rpk[(size_t)(qbase + lhi * 4 + r) * 1024 + kk * 64 + kc4 * 16 + llo];
    }
    __syncthreads();

    f32x4 s[4];
    __builtin_amdgcn_s_setprio(1);
#pragma unroll
    for (int kc4 = 0; kc4 < 4; ++kc4) {
      f32x4 c = {};
#pragma unroll
      for (int kf = 0; kf < 2; ++kf) {
        int kr = kc4 * 16 + llo;
        s16x8 bk = *(const s16x8*)&kbuf[kr * 64 + ((((kf << 2) | lhi) ^ (kr & 7)) << 3)];
        c = mfma16(kf ? aq1 : aq0, bk, c);
      }
      s[kc4] = c;
    }
    __builtin_amdgcn_s_setprio(0);

    if (gather) {
#pragma unroll
      for (int kc4 = 0; kc4 < 4; ++kc4)
#pragma unroll
        for (int r = 0; r < 4; ++r) {
          u16 v = pp[kc4 * 4 + r];
          s[kc4][r] += bf2f(tsb[0][tbase[r] + (v & 255)]) + bf2f(tsb[1][tbase[r] + (v >> 8)]);
        }
    }

    // defer-max (T13)
    float smx[4];
#pragma unroll
    for (int r = 0; r < 4; ++r)
      smx[r] = fmaxf(fmaxf(s[0][r], s[1][r]), fmaxf(s[2][r], s[3][r]));
    int ok = 1;
#pragma unroll
    for (int r = 0; r < 4; ++r) ok &= (smx[r] <= mrun[r] + 8.0f);
    if (!__all(ok)) {
#pragma unroll
      for (int msk = 1; msk < 16; msk <<= 1)
#pragma unroll
        for (int r = 0; r < 4; ++r)
          smx[r] = fmaxf(smx[r], __shfl_xor(smx[r], msk, 64));
#pragma unroll
      for (int r = 0; r < 4; ++r) {
        float mn = fmaxf(mrun[r], smx[r]);
        float corr = __expf(mrun[r] - mn);
        mrun[r] = mn;
        lrun[r] *= corr;
#pragma unroll
        for (int dc = 0; dc < 4; ++dc) accO[dc][r] *= corr;
      }
    }
#pragma unroll
    for (int r = 0; r < 4; ++r) {
      float ls = 0.f;
#pragma unroll
      for (int kc4 = 0; kc4 < 4; ++kc4) {
        float pv = __expf(s[kc4][r] - mrun[r]);
        ls += pv;
        pbuf[w][(lhi * 4 + r) * 72 + kc4 * 16 + llo] = f2bf(pv);
      }
      lrun[r] += ls;
    }

    asm volatile("s_waitcnt lgkmcnt(0)" ::: "memory");
    __builtin_amdgcn_sched_barrier(0);

    __builtin_amdgcn_s_setprio(1);
#pragma unroll
    for (int kf = 0; kf < 2; ++kf) {
      s16x8 ap = *(const s16x8*)&pbuf[w][llo * 72 + kf * 32 + lhi * 8];
#pragma unroll
      for (int dc = 0; dc < 4; ++dc) {
        int dr = dc * 16 + llo;
        s16x8 bv = *(const s16x8*)&vbuf[dr * 64 + ((((kf << 2) | lhi) ^ (dr & 7)) << 3)];
        accO[dc] = mfma16(ap, bv, accO[dc]);
      }
    }
    __builtin_amdgcn_s_setprio(0);
    __syncthreads();
  };

  for (int kt = 0; kt < 16; ++kt) tile(KgA, VgA, kt, true);    // reg keys + RPE
  for (int kt = 0; kt < 16; ++kt) tile(KgB, VgB, kt, false);   // sum keys

  // epilogue l-reduction
#pragma unroll
  for (int msk = 1; msk < 16; msk <<= 1)
#pragma unroll
    for (int r = 0; r < 4; ++r) lrun[r] += __shfl_xor(lrun[r], msk, 64);

#pragma unroll
  for (int dc = 0; dc < 4; ++dc)
#pragma unroll
    for (int r = 0; r < 4; ++r) {
      int q = qbase + lhi * 4 + r;
      float o = accO[dc][r] / lrun[r];
      attn_out[((size_t)b * 1024 + q) * 768 + hh * 64 + dc * 16 + llo] = f2bf(o);
    }
}

// ---------------- launch ----------------
extern "C" void kernel_launch(void* const* d_in, const int* in_sizes, int n_in,
                              void* d_out, int out_size, void* d_ws, size_t ws_size,
                              hipStream_t stream) {
  (void)in_sizes; (void)n_in; (void)out_size; (void)ws_size;
  const float* x     = (const float*)d_in[0];
  const int*   rp0   = (const int*)d_in[1];
  const int*   rp1   = (const int*)d_in[2];
  const float* re0   = (const float*)d_in[3];
  const float* re1   = (const float*)d_in[4];
  const float* Wq_r  = (const float*)d_in[5];  const float* bq_r = (const float*)d_in[6];
  const float* Wk_r  = (const float*)d_in[7];  const float* bk_r = (const float*)d_in[8];
  const float* Wv_r  = (const float*)d_in[9];  const float* bv_r = (const float*)d_in[10];
  const float* Wq_s  = (const float*)d_in[11]; const float* bq_s = (const float*)d_in[12];
  const float* Wk_s  = (const float*)d_in[13]; const float* bk_s = (const float*)d_in[14];
  const float* Wv_s  = (const float*)d_in[15]; const float* bv_s = (const float*)d_in[16];
  const float* Wk2   = (const float*)d_in[17]; const float* bk2  = (const float*)d_in[18];
  const float* Wv2   = (const float*)d_in[19]; const float* bv2  = (const float*)d_in[20];
  const float* Wrel0 = (const float*)d_in[21]; const float* brel0 = (const float*)d_in[22];
  const float* Wrel1 = (const float*)d_in[23]; const float* brel1 = (const float*)d_in[24];
  const float* Wo    = (const float*)d_in[25]; const float* bo   = (const float*)d_in[26];
  float* out = (float*)d_out;

  char* wp = (char*)d_ws;
  auto carve = [&](size_t bytes) {
    char* r = wp;
    wp += (bytes + 255) & ~(size_t)255;
    return r;
  };
  u16* xb     = (u16*)carve((size_t)PE * 2);
  u16* Wcat1  = (u16*)carve((size_t)4608 * 768 * 2);
  u16* Wcat2  = (u16*)carve((size_t)1536 * 768 * 2);
  u16* Wrel0b = (u16*)carve((size_t)768 * 768 * 2);
  u16* Wrel1b = (u16*)carve((size_t)768 * 768 * 2);
  u16* Wob    = (u16*)carve((size_t)768 * 768 * 2);
  u16* relA0  = (u16*)carve((size_t)128 * 768 * 2);
  u16* relA1  = (u16*)carve((size_t)128 * 768 * 2);
  u16* qkv    = (u16*)carve((size_t)6 * PE * 2);   // Qr,Kr,Vrt,Qs,Ks,Vst
  u16* k2v2   = (u16*)carve((size_t)2 * PE * 2);   // K2, V2t
  u16* tb0    = (u16*)carve((size_t)12 * 80 * 64 * 2);
  u16* tb1    = (u16*)carve((size_t)12 * 80 * 64 * 2);
  u16* rpk    = (u16*)carve((size_t)1024 * 1024 * 2);
  u16* sumx   = (u16*)carve((size_t)PE * 2);
  u16* aout   = (u16*)carve((size_t)PE * 2);

  const int wn_ = 768 * 768;
  CastJobs J;
  const float* srcs[14] = {x, Wq_r, Wk_r, Wv_r, Wq_s, Wk_s, Wv_s, Wk2, Wv2, Wrel0, Wrel1, Wo, re0, re1};
  u16* dsts[14] = {xb, Wcat1, Wcat1 + wn_, Wcat1 + 2 * wn_, Wcat1 + 3 * wn_, Wcat1 + 4 * wn_,
                   Wcat1 + 5 * wn_, Wcat2, Wcat2 + wn_, Wrel0b, Wrel1b, Wob, relA0, relA1};
  int ns[14] = {PE, wn_, wn_, wn_, wn_, wn_, wn_, wn_, wn_, wn_, wn_, wn_, 65 * 768, 65 * 768};
  for (int i = 0; i < 14; ++i) { J.src[i] = srcs[i]; J.dst[i] = dsts[i]; J.n[i] = ns[i]; }
  cast_bf16_kernel<<<dim3(1536, 14), 256, 0, stream>>>(J);

  pack_rp_kernel<<<dim3(512), 256, 0, stream>>>(rp0, rp1, rpk);

  GemmP g1{};
  g1.A = xb; g1.Bw = Wcat1;
  g1.bias[0] = bq_r; g1.bias[1] = bk_r; g1.bias[2] = bv_r;
  g1.bias[3] = bq_s; g1.bias[4] = bk_s; g1.bias[5] = bv_s;
  g1.out_bf = qkv; g1.epi = 0;
  gemm_bt<<<dim3(32, 36), 256, 0, stream>>>(g1);

  GemmP gt0{}; gt0.A = relA0; gt0.Bw = Wrel0b; gt0.bias[0] = brel0; gt0.out_bf = tb0; gt0.epi = 2;
  gemm_bt<<<dim3(1, 6), 256, 0, stream>>>(gt0);
  GemmP gt1{}; gt1.A = relA1; gt1.Bw = Wrel1b; gt1.bias[0] = brel1; gt1.out_bf = tb1; gt1.epi = 2;
  gemm_bt<<<dim3(1, 6), 256, 0, stream>>>(gt1);

  sum_attn_kernel<<<dim3(768), 256, 0, stream>>>(qkv + (size_t)3 * PE, qkv + (size_t)4 * PE,
                                                 qkv + (size_t)5 * PE, sumx);

  GemmP g2{};
  g2.A = sumx; g2.Bw = Wcat2; g2.bias[0] = bk2; g2.bias[1] = bv2;
  g2.out_bf = k2v2; g2.epi = 1;
  gemm_bt<<<dim3(32, 12), 256, 0, stream>>>(g2);

  reg_attn_kernel<<<dim3(768), 256, 0, stream>>>(qkv, qkv + (size_t)PE, qkv + (size_t)2 * PE,
                                                 k2v2, k2v2 + (size_t)PE, tb0, tb1, rpk, aout);

  GemmP gf{};
  gf.A = aout; gf.Bw = Wob; gf.bias[0] = bo; gf.out_f = out; gf.epi = 3;
  gemm_bt<<<dim3(32, 6), 256, 0, stream>>>(gf);
}

// Round 7
// 366.348 us; speedup vs baseline: 1.1870x; 1.0551x over previous
//
#include <hip/hip_runtime.h>
#include <hip/hip_bf16.h>
#include <stdint.h>

// SumThenRegRpeSelfAttention: B=4 T=1024 E=768 H=12 DH=64 P=65
// cast -> [stage1 GEMM qkv x6] -> sum-attn -> [k2v2 GEMM] -> reg-attn(+RPE) -> [out GEMM]
// Attention kernels use swapped-QK^T (scores q-in-cols => per-lane softmax).

#define DEV __device__ __forceinline__

using f32x4 = __attribute__((ext_vector_type(4))) float;
using s16x8 = __attribute__((ext_vector_type(8))) short;
using s16x4 = __attribute__((ext_vector_type(4))) short;
using i32x4 = __attribute__((ext_vector_type(4))) int;
using u32x2 = __attribute__((ext_vector_type(2))) unsigned int;
using fvec4 = __attribute__((ext_vector_type(4))) float;
using u16 = unsigned short;

static constexpr int KD = 768;            // inner K of every GEMM
static constexpr int PE = 4096 * 768;     // elems per projection tensor
static constexpr float QSCL = 0.18033688011112042f;  // 0.125 * log2(e)

DEV u16 f2bf(float f) {
  uint32_t u = __builtin_bit_cast(uint32_t, f);
  u += 0x7FFF + ((u >> 16) & 1);
  return (u16)(u >> 16);
}
DEV float bf2f(u16 h) { return __builtin_bit_cast(float, (uint32_t)h << 16); }
DEV unsigned int cvtpk(float a, float b) {  // lo=bf16(a), hi=bf16(b)
  unsigned int r;
  asm("v_cvt_pk_bf16_f32 %0, %1, %2" : "=v"(r) : "v"(a), "v"(b));
  return r;
}

DEV void gload16(const void* g, void* l) {
  __builtin_amdgcn_global_load_lds((const __attribute__((address_space(1))) void*)g,
                                   (__attribute__((address_space(3))) void*)l, 16, 0, 0);
}
DEV f32x4 mfma16(s16x8 a, s16x8 b, f32x4 c) {
  return __builtin_amdgcn_mfma_f32_16x16x32_bf16(a, b, c, 0, 0, 0);
}

// ---------------- cast f32 -> bf16 (14 jobs) ----------------
struct CastJobs {
  const float* src[14];
  u16* dst[14];
  int n[14];
};
__global__ __launch_bounds__(256) void cast_bf16_kernel(CastJobs J) {
  const int job = blockIdx.y;
  const int i = (blockIdx.x * 256 + threadIdx.x) * 8;
  if (i >= J.n[job]) return;
  const fvec4* s = (const fvec4*)(J.src[job] + i);
  fvec4 a = s[0], b = s[1];
  s16x8 o;
  o[0] = (short)f2bf(a[0]); o[1] = (short)f2bf(a[1]);
  o[2] = (short)f2bf(a[2]); o[3] = (short)f2bf(a[3]);
  o[4] = (short)f2bf(b[0]); o[5] = (short)f2bf(b[1]);
  o[6] = (short)f2bf(b[2]); o[7] = (short)f2bf(b[3]);
  *(s16x8*)(J.dst[job] + i) = o;
}

// ---------------- pack rel_pos0|rel_pos1 into u8 pairs ----------------
__global__ __launch_bounds__(256) void pack_rp_kernel(const int* rp0, const int* rp1, u16* outp) {
  const int i = (blockIdx.x * 256 + threadIdx.x) * 8;
  i32x4 a0 = *(const i32x4*)(rp0 + i), a1 = *(const i32x4*)(rp0 + i + 4);
  i32x4 b0 = *(const i32x4*)(rp1 + i), b1 = *(const i32x4*)(rp1 + i + 4);
  s16x8 o;
  o[0] = (short)(a0[0] | (b0[0] << 8));
  o[1] = (short)(a0[1] | (b0[1] << 8));
  o[2] = (short)(a0[2] | (b0[2] << 8));
  o[3] = (short)(a0[3] | (b0[3] << 8));
  o[4] = (short)(a1[0] | (b1[0] << 8));
  o[5] = (short)(a1[1] | (b1[1] << 8));
  o[6] = (short)(a1[2] | (b1[2] << 8));
  o[7] = (short)(a1[3] | (b1[3] << 8));
  *(s16x8*)(outp + i) = o;
}

// ---------------- generic GEMM: C = A(bf16, MxK) * W(bf16, NxK)^T ----------------
// epi: 0=stage1 (6 projections, head-major, V transposed), 1=k2v2, 2=rel table(s), 3=final f32
struct GemmP {
  const u16* A;
  const u16* Bw;
  const float* bias[6];
  u16* out_bf;
  float* out_f;
  const u16* A2;      // second table job (epi 2, blockIdx.z==1)
  const u16* Bw2;
  u16* out2;
  int epi;
};

__global__ __launch_bounds__(256) void gemm_bt(GemmP p) {
  __shared__ __align__(16) u16 As[128 * 64];
  __shared__ __align__(16) u16 Bs[128 * 64];
  const int tid = threadIdx.x;
  const int m0 = blockIdx.x * 128, n0 = blockIdx.y * 128;
  const int zz = blockIdx.z;
  const u16* Ag = (zz ? p.A2 : p.A) + (size_t)m0 * KD;
  const u16* Bg = (zz ? p.Bw2 : p.Bw) + (size_t)n0 * KD;
  const int lane = tid & 63, wid = tid >> 6;
  const int wm = (wid >> 1) * 64, wn = (wid & 1) * 64;
  const int lhi = lane >> 4, llo = lane & 15;

  uint ldso[4], srco[4];
#pragma unroll
  for (int j = 0; j < 4; ++j) {
    uint o = tid * 16 + j * 4096;
    uint row = o >> 7, kc = (o >> 4) & 7;
    ldso[j] = o;
    srco[j] = row * KD + ((kc ^ (row & 7)) << 3);
  }

  f32x4 acc[4][4] = {};

  for (int kt = 0; kt < 12; ++kt) {
    const int k0 = kt * 64;
#pragma unroll
    for (int j = 0; j < 4; ++j) gload16(Ag + srco[j] + k0, (char*)As + ldso[j]);
#pragma unroll
    for (int j = 0; j < 4; ++j) gload16(Bg + srco[j] + k0, (char*)Bs + ldso[j]);
    __syncthreads();
#pragma unroll
    for (int kf = 0; kf < 2; ++kf) {
      s16x8 av[4], bv[4];
#pragma unroll
      for (int mf = 0; mf < 4; ++mf) {
        int r = wm + mf * 16 + llo;
        av[mf] = *(const s16x8*)&As[r * 64 + ((((kf << 2) | lhi) ^ (r & 7)) << 3)];
      }
#pragma unroll
      for (int nf = 0; nf < 4; ++nf) {
        int r = wn + nf * 16 + llo;
        bv[nf] = *(const s16x8*)&Bs[r * 64 + ((((kf << 2) | lhi) ^ (r & 7)) << 3)];
      }
#pragma unroll
      for (int mf = 0; mf < 4; ++mf)
#pragma unroll
        for (int nf = 0; nf < 4; ++nf)
          acc[mf][nf] = mfma16(av[mf], bv[nf], acc[mf][nf]);
    }
    __syncthreads();
  }

  const int epi = p.epi;
#pragma unroll
  for (int nf = 0; nf < 4; ++nf) {
    const int n = n0 + wn + nf * 16 + llo;
    int proj = 0, n1 = n, hh, dd;
    float bias, scale = 1.0f;
    if (epi <= 1) {
      proj = n / 768; n1 = n - proj * 768;
      hh = n1 >> 6; dd = n1 & 63;
      bias = p.bias[proj][n1];
      if (epi == 0 && (proj == 0 || proj == 3)) scale = QSCL;  // fold SCALE*log2e into Q
    } else {
      hh = n >> 6; dd = n & 63;
      bias = p.bias[zz ? 1 : 0][n];
    }
#pragma unroll
    for (int mf = 0; mf < 4; ++mf) {
      f32x4 c = acc[mf][nf];
      const int mb = m0 + wm + mf * 16 + lhi * 4;
      if (epi == 3) {
#pragma unroll
        for (int r = 0; r < 4; ++r)
          p.out_f[(size_t)(mb + r) * 768 + n] = c[r] + bias;
      } else if (epi == 2) {
        u16* ob = zz ? p.out2 : p.out_bf;
#pragma unroll
        for (int r = 0; r < 4; ++r) {
          int m = mb + r;
          if (m < 80) ob[((size_t)hh * 80 + m) * 64 + dd] = f2bf(c[r] + bias);
        }
      } else {
        const bool vlay = (epi == 0) ? (proj == 2 || proj == 5) : (proj == 1);
        if (vlay) {
          const int b = mb >> 10, t = mb & 1023;
          const int bh = b * 12 + hh;
          s16x4 o4;
          o4[0] = (short)f2bf((c[0] + bias) * scale);
          o4[1] = (short)f2bf((c[1] + bias) * scale);
          o4[2] = (short)f2bf((c[2] + bias) * scale);
          o4[3] = (short)f2bf((c[3] + bias) * scale);
          *(s16x4*)&p.out_bf[(size_t)proj * PE + ((size_t)(bh * 64 + dd)) * 1024 + t] = o4;
        } else {
#pragma unroll
          for (int r = 0; r < 4; ++r) {
            int m = mb + r;
            int b = m >> 10, t = m & 1023;
            int bh = b * 12 + hh;
            p.out_bf[(size_t)proj * PE + ((size_t)(bh * 1024 + t)) * 64 + dd] =
                f2bf((c[r] + bias) * scale);
          }
        }
      }
    }
  }
}

// ---------------- sum-branch flash attention (swapped QK^T) ----------------
// 1-D grid 768 (XCD-swizzled), 256 thr, QB=64 (16 q-rows per wave), KB=64
__global__ __launch_bounds__(256) void sum_attn_kernel(const u16* Qs, const u16* Ks,
                                                       const u16* Vst, u16* sum_x) {
  __shared__ __align__(16) u16 kbuf[64 * 64];
  __shared__ __align__(16) u16 vbuf[64 * 64];
  __shared__ __align__(16) u16 pbuf[4][16 * 72];
  const int tid = threadIdx.x, lane = tid & 63, w = tid >> 6;
  const int lhi = lane >> 4, llo = lane & 15;
  const int bid = blockIdx.x;
  const int vid = (bid & 7) * 96 + (bid >> 3);
  const int qt = vid & 15, bh = vid >> 4;
  const int qbase = qt * 64 + w * 16;

  const u16* Qg = Qs + ((size_t)bh * 1024 + qbase + llo) * 64;
  s16x8 aq0 = *(const s16x8*)(Qg + lhi * 8);
  s16x8 aq1 = *(const s16x8*)(Qg + 32 + lhi * 8);

  f32x4 accO[4] = {};
  float mrun = -1e30f, lrun = 0.f;

  uint so[2], srow[2], sswz[2];
#pragma unroll
  for (int j = 0; j < 2; ++j) {
    uint o = tid * 16 + j * 4096;
    so[j] = o; srow[j] = o >> 7;
    sswz[j] = (((o >> 4) & 7) ^ (srow[j] & 7)) << 3;
  }
  const u16* Kg = Ks + (size_t)bh * 65536;
  const u16* Vg = Vst + (size_t)bh * 65536;

  for (int kt = 0; kt < 16; ++kt) {
#pragma unroll
    for (int j = 0; j < 2; ++j) {
      gload16(Kg + (size_t)kt * 4096 + srow[j] * 64 + sswz[j], (char*)kbuf + so[j]);
      gload16(Vg + (size_t)srow[j] * 1024 + kt * 64 + sswz[j], (char*)vbuf + so[j]);
    }
    __syncthreads();

    // scores: S[k=kc4*16+lhi*4+r][q=llo]  (swapped operands)
    f32x4 s[4];
    __builtin_amdgcn_s_setprio(1);
#pragma unroll
    for (int kc4 = 0; kc4 < 4; ++kc4) {
      f32x4 c = {};
#pragma unroll
      for (int kf = 0; kf < 2; ++kf) {
        int kr = kc4 * 16 + llo;
        s16x8 bk = *(const s16x8*)&kbuf[kr * 64 + ((((kf << 2) | lhi) ^ (kr & 7)) << 3)];
        c = mfma16(bk, kf ? aq1 : aq0, c);
      }
      s[kc4] = c;
    }
    __builtin_amdgcn_s_setprio(0);

    // per-lane softmax state (one q-row per lane)
    float smx = s[0][0];
#pragma unroll
    for (int kc4 = 0; kc4 < 4; ++kc4)
#pragma unroll
      for (int r = 0; r < 4; ++r) smx = fmaxf(smx, s[kc4][r]);
    if (!__all(smx <= mrun + 8.0f)) {
      float mall = fmaxf(smx, __shfl_xor(smx, 16, 64));
      mall = fmaxf(mall, __shfl_xor(mall, 32, 64));
      float mn = fmaxf(mrun, mall);
      float corr = exp2f(mrun - mn);
      mrun = mn;
      lrun *= corr;
      float cf[4];
#pragma unroll
      for (int r = 0; r < 4; ++r) cf[r] = __shfl(corr, lhi * 4 + r, 64);
#pragma unroll
      for (int dc = 0; dc < 4; ++dc)
#pragma unroll
        for (int r = 0; r < 4; ++r) accO[dc][r] *= cf[r];
    }
    float ls = 0.f;
#pragma unroll
    for (int kc4 = 0; kc4 < 4; ++kc4) {
      float p0 = exp2f(s[kc4][0] - mrun), p1 = exp2f(s[kc4][1] - mrun);
      float p2 = exp2f(s[kc4][2] - mrun), p3 = exp2f(s[kc4][3] - mrun);
      ls += (p0 + p1) + (p2 + p3);
      u32x2 pk; pk[0] = cvtpk(p0, p1); pk[1] = cvtpk(p2, p3);
      *(u32x2*)&pbuf[w][llo * 72 + kc4 * 16 + lhi * 4] = pk;
    }
    lrun += ls;

    __builtin_amdgcn_s_setprio(1);
#pragma unroll
    for (int kf = 0; kf < 2; ++kf) {
      s16x8 ap = *(const s16x8*)&pbuf[w][llo * 72 + kf * 32 + lhi * 8];
#pragma unroll
      for (int dc = 0; dc < 4; ++dc) {
        int dr = dc * 16 + llo;
        s16x8 bv = *(const s16x8*)&vbuf[dr * 64 + ((((kf << 2) | lhi) ^ (dr & 7)) << 3)];
        accO[dc] = mfma16(ap, bv, accO[dc]);
      }
    }
    __builtin_amdgcn_s_setprio(0);
    __syncthreads();
  }

  lrun += __shfl_xor(lrun, 16, 64);
  lrun += __shfl_xor(lrun, 32, 64);
  float linv[4];
#pragma unroll
  for (int r = 0; r < 4; ++r) linv[r] = 1.0f / __shfl(lrun, lhi * 4 + r, 64);

  const int b = bh / 12, hh = bh - b * 12;
#pragma unroll
  for (int dc = 0; dc < 4; ++dc)
#pragma unroll
    for (int r = 0; r < 4; ++r) {
      int q = qbase + lhi * 4 + r;
      sum_x[((size_t)b * 1024 + q) * 768 + hh * 64 + dc * 16 + llo] = f2bf(accO[dc][r] * linv[r]);
    }
}

// ---------------- reg-branch flash attention with RPE gather (swapped QK^T) ----------------
__global__ __launch_bounds__(256) void reg_attn_kernel(
    const u16* Qr, const u16* Kr, const u16* Vrt,
    const u16* K2, const u16* V2t,
    const u16* tab0, const u16* tab1,
    const u16* rpk, u16* attn_out) {
  __shared__ __align__(16) u16 kbuf[64 * 64];
  __shared__ __align__(16) u16 vbuf[64 * 64];
  __shared__ __align__(16) u16 tsb0[64 * 80];
  __shared__ __align__(16) u16 tsb1[64 * 80];
  __shared__ __align__(16) u16 pbuf[4][16 * 72];
  const int tid = threadIdx.x, lane = tid & 63, w = tid >> 6;
  const int lhi = lane >> 4, llo = lane & 15;
  const int bid = blockIdx.x;
  const int vid = (bid & 7) * 96 + (bid >> 3);
  const int qt = vid & 15, bh = vid >> 4;
  const int b = bh / 12, hh = bh - b * 12;
  const int qbase = qt * 64 + w * 16;
  const int qloc = w * 16 + llo;       // this lane's q-row (block-local) in score layout

  const u16* Qg = Qr + ((size_t)bh * 1024 + qbase + llo) * 64;
  s16x8 aq0 = *(const s16x8*)(Qg + lhi * 8);
  s16x8 aq1 = *(const s16x8*)(Qg + 32 + lhi * 8);

  // ts[p][q] = table[p] . q  (swapped: q in cols). Write packed pairs.
#pragma unroll
  for (int tt = 0; tt < 2; ++tt) {
    const u16* tb = tt ? tab1 : tab0;
    u16* dst = tt ? tsb1 : tsb0;
#pragma unroll
    for (int pf = 0; pf < 5; ++pf) {
      f32x4 c = {};
#pragma unroll
      for (int kf = 0; kf < 2; ++kf) {
        s16x8 bt = *(const s16x8*)(tb + ((size_t)hh * 80 + pf * 16 + llo) * 64 + kf * 32 + lhi * 8);
        c = mfma16(bt, kf ? aq1 : aq0, c);
      }
      u32x2 pk; pk[0] = cvtpk(c[0], c[1]); pk[1] = cvtpk(c[2], c[3]);
      *(u32x2*)&dst[(w * 16 + llo) * 80 + pf * 16 + lhi * 4] = pk;
    }
  }
  __syncthreads();

  f32x4 accO[4] = {};
  float mrun = -1e30f, lrun = 0.f;

  uint so[2], srow[2], sswz[2];
#pragma unroll
  for (int j = 0; j < 2; ++j) {
    uint o = tid * 16 + j * 4096;
    so[j] = o; srow[j] = o >> 7;
    sswz[j] = (((o >> 4) & 7) ^ (srow[j] & 7)) << 3;
  }
  const u16* KgA = Kr + (size_t)bh * 65536;
  const u16* KgB = K2 + (size_t)bh * 65536;
  const u16* VgA = Vrt + (size_t)bh * 65536;
  const u16* VgB = V2t + (size_t)bh * 65536;

  auto tile = [&](const u16* Kg, const u16* Vg, int kk, bool gather) {
#pragma unroll
    for (int j = 0; j < 2; ++j) {
      gload16(Kg + (size_t)kk * 4096 + srow[j] * 64 + sswz[j], (char*)kbuf + so[j]);
      gload16(Vg + (size_t)srow[j] * 1024 + kk * 64 + sswz[j], (char*)vbuf + so[j]);
    }
    // vector-load gather indices before the barrier (latency hides under vmcnt drain)
    s16x4 pp4[4];
    if (gather) {
#pragma unroll
      for (int kc4 = 0; kc4 < 4; ++kc4)
        pp4[kc4] = *(const s16x4*)&rpk[(size_t)(qbase + llo) * 1024 + kk * 64 + kc4 * 16 + lhi * 4];
    }
    __syncthreads();

    f32x4 s[4];
    __builtin_amdgcn_s_setprio(1);
#pragma unroll
    for (int kc4 = 0; kc4 < 4; ++kc4) {
      f32x4 c = {};
#pragma unroll
      for (int kf = 0; kf < 2; ++kf) {
        int kr = kc4 * 16 + llo;
        s16x8 bk = *(const s16x8*)&kbuf[kr * 64 + ((((kf << 2) | lhi) ^ (kr & 7)) << 3)];
        c = mfma16(bk, kf ? aq1 : aq0, c);
      }
      s[kc4] = c;
    }
    __builtin_amdgcn_s_setprio(0);

    if (gather) {
#pragma unroll
      for (int kc4 = 0; kc4 < 4; ++kc4)
#pragma unroll
        for (int r = 0; r < 4; ++r) {
          int v = (u16)pp4[kc4][r];
          s[kc4][r] += bf2f(tsb0[qloc * 80 + (v & 255)]) + bf2f(tsb1[qloc * 80 + (v >> 8)]);
        }
    }

    float smx = s[0][0];
#pragma unroll
    for (int kc4 = 0; kc4 < 4; ++kc4)
#pragma unroll
      for (int r = 0; r < 4; ++r) smx = fmaxf(smx, s[kc4][r]);
    if (!__all(smx <= mrun + 8.0f)) {
      float mall = fmaxf(smx, __shfl_xor(smx, 16, 64));
      mall = fmaxf(mall, __shfl_xor(mall, 32, 64));
      float mn = fmaxf(mrun, mall);
      float corr = exp2f(mrun - mn);
      mrun = mn;
      lrun *= corr;
      float cf[4];
#pragma unroll
      for (int r = 0; r < 4; ++r) cf[r] = __shfl(corr, lhi * 4 + r, 64);
#pragma unroll
      for (int dc = 0; dc < 4; ++dc)
#pragma unroll
        for (int r = 0; r < 4; ++r) accO[dc][r] *= cf[r];
    }
    float ls = 0.f;
#pragma unroll
    for (int kc4 = 0; kc4 < 4; ++kc4) {
      float p0 = exp2f(s[kc4][0] - mrun), p1 = exp2f(s[kc4][1] - mrun);
      float p2 = exp2f(s[kc4][2] - mrun), p3 = exp2f(s[kc4][3] - mrun);
      ls += (p0 + p1) + (p2 + p3);
      u32x2 pk; pk[0] = cvtpk(p0, p1); pk[1] = cvtpk(p2, p3);
      *(u32x2*)&pbuf[w][llo * 72 + kc4 * 16 + lhi * 4] = pk;
    }
    lrun += ls;

    __builtin_amdgcn_s_setprio(1);
#pragma unroll
    for (int kf = 0; kf < 2; ++kf) {
      s16x8 ap = *(const s16x8*)&pbuf[w][llo * 72 + kf * 32 + lhi * 8];
#pragma unroll
      for (int dc = 0; dc < 4; ++dc) {
        int dr = dc * 16 + llo;
        s16x8 bv = *(const s16x8*)&vbuf[dr * 64 + ((((kf << 2) | lhi) ^ (dr & 7)) << 3)];
        accO[dc] = mfma16(ap, bv, accO[dc]);
      }
    }
    __builtin_amdgcn_s_setprio(0);
    __syncthreads();
  };

  for (int kt = 0; kt < 16; ++kt) tile(KgA, VgA, kt, true);    // reg keys + RPE
  for (int kt = 0; kt < 16; ++kt) tile(KgB, VgB, kt, false);   // sum keys

  lrun += __shfl_xor(lrun, 16, 64);
  lrun += __shfl_xor(lrun, 32, 64);
  float linv[4];
#pragma unroll
  for (int r = 0; r < 4; ++r) linv[r] = 1.0f / __shfl(lrun, lhi * 4 + r, 64);

#pragma unroll
  for (int dc = 0; dc < 4; ++dc)
#pragma unroll
    for (int r = 0; r < 4; ++r) {
      int q = qbase + lhi * 4 + r;
      attn_out[((size_t)b * 1024 + q) * 768 + hh * 64 + dc * 16 + llo] = f2bf(accO[dc][r] * linv[r]);
    }
}

// ---------------- launch ----------------
extern "C" void kernel_launch(void* const* d_in, const int* in_sizes, int n_in,
                              void* d_out, int out_size, void* d_ws, size_t ws_size,
                              hipStream_t stream) {
  (void)in_sizes; (void)n_in; (void)out_size; (void)ws_size;
  const float* x     = (const float*)d_in[0];
  const int*   rp0   = (const int*)d_in[1];
  const int*   rp1   = (const int*)d_in[2];
  const float* re0   = (const float*)d_in[3];
  const float* re1   = (const float*)d_in[4];
  const float* Wq_r  = (const float*)d_in[5];  const float* bq_r = (const float*)d_in[6];
  const float* Wk_r  = (const float*)d_in[7];  const float* bk_r = (const float*)d_in[8];
  const float* Wv_r  = (const float*)d_in[9];  const float* bv_r = (const float*)d_in[10];
  const float* Wq_s  = (const float*)d_in[11]; const float* bq_s = (const float*)d_in[12];
  const float* Wk_s  = (const float*)d_in[13]; const float* bk_s = (const float*)d_in[14];
  const float* Wv_s  = (const float*)d_in[15]; const float* bv_s = (const float*)d_in[16];
  const float* Wk2   = (const float*)d_in[17]; const float* bk2  = (const float*)d_in[18];
  const float* Wv2   = (const float*)d_in[19]; const float* bv2  = (const float*)d_in[20];
  const float* Wrel0 = (const float*)d_in[21]; const float* brel0 = (const float*)d_in[22];
  const float* Wrel1 = (const float*)d_in[23]; const float* brel1 = (const float*)d_in[24];
  const float* Wo    = (const float*)d_in[25]; const float* bo   = (const float*)d_in[26];
  float* out = (float*)d_out;

  char* wp = (char*)d_ws;
  auto carve = [&](size_t bytes) {
    char* r = wp;
    wp += (bytes + 255) & ~(size_t)255;
    return r;
  };
  u16* xb     = (u16*)carve((size_t)PE * 2);
  u16* Wcat1  = (u16*)carve((size_t)4608 * 768 * 2);
  u16* Wcat2  = (u16*)carve((size_t)1536 * 768 * 2);
  u16* Wrel0b = (u16*)carve((size_t)768 * 768 * 2);
  u16* Wrel1b = (u16*)carve((size_t)768 * 768 * 2);
  u16* Wob    = (u16*)carve((size_t)768 * 768 * 2);
  u16* relA0  = (u16*)carve((size_t)128 * 768 * 2);
  u16* relA1  = (u16*)carve((size_t)128 * 768 * 2);
  u16* qkv    = (u16*)carve((size_t)6 * PE * 2);   // Qr,Kr,Vrt,Qs,Ks,Vst
  u16* k2v2   = (u16*)carve((size_t)2 * PE * 2);   // K2, V2t
  u16* tb0    = (u16*)carve((size_t)12 * 80 * 64 * 2);
  u16* tb1    = (u16*)carve((size_t)12 * 80 * 64 * 2);
  u16* rpk    = (u16*)carve((size_t)1024 * 1024 * 2);
  u16* sumx   = (u16*)carve((size_t)PE * 2);
  u16* aout   = (u16*)carve((size_t)PE * 2);

  const int wn_ = 768 * 768;
  CastJobs J;
  const float* srcs[14] = {x, Wq_r, Wk_r, Wv_r, Wq_s, Wk_s, Wv_s, Wk2, Wv2, Wrel0, Wrel1, Wo, re0, re1};
  u16* dsts[14] = {xb, Wcat1, Wcat1 + wn_, Wcat1 + 2 * wn_, Wcat1 + 3 * wn_, Wcat1 + 4 * wn_,
                   Wcat1 + 5 * wn_, Wcat2, Wcat2 + wn_, Wrel0b, Wrel1b, Wob, relA0, relA1};
  int ns[14] = {PE, wn_, wn_, wn_, wn_, wn_, wn_, wn_, wn_, wn_, wn_, wn_, 65 * 768, 65 * 768};
  for (int i = 0; i < 14; ++i) { J.src[i] = srcs[i]; J.dst[i] = dsts[i]; J.n[i] = ns[i]; }
  cast_bf16_kernel<<<dim3(1536, 14), 256, 0, stream>>>(J);

  pack_rp_kernel<<<dim3(512), 256, 0, stream>>>(rp0, rp1, rpk);

  GemmP g1{};
  g1.A = xb; g1.Bw = Wcat1;
  g1.bias[0] = bq_r; g1.bias[1] = bk_r; g1.bias[2] = bv_r;
  g1.bias[3] = bq_s; g1.bias[4] = bk_s; g1.bias[5] = bv_s;
  g1.out_bf = qkv; g1.epi = 0;
  gemm_bt<<<dim3(32, 36), 256, 0, stream>>>(g1);

  GemmP gt{};
  gt.A = relA0; gt.Bw = Wrel0b; gt.bias[0] = brel0; gt.out_bf = tb0;
  gt.A2 = relA1; gt.Bw2 = Wrel1b; gt.bias[1] = brel1; gt.out2 = tb1;
  gt.epi = 2;
  gemm_bt<<<dim3(1, 6, 2), 256, 0, stream>>>(gt);

  sum_attn_kernel<<<dim3(768), 256, 0, stream>>>(qkv + (size_t)3 * PE, qkv + (size_t)4 * PE,
                                                 qkv + (size_t)5 * PE, sumx);

  GemmP g2{};
  g2.A = sumx; g2.Bw = Wcat2; g2.bias[0] = bk2; g2.bias[1] = bv2;
  g2.out_bf = k2v2; g2.epi = 1;
  gemm_bt<<<dim3(32, 12), 256, 0, stream>>>(g2);

  reg_attn_kernel<<<dim3(768), 256, 0, stream>>>(qkv, qkv + (size_t)PE, qkv + (size_t)2 * PE,
                                                 k2v2, k2v2 + (size_t)PE, tb0, tb1, rpk, aout);

  GemmP gf{};
  gf.A = aout; gf.Bw = Wob; gf.bias[0] = bo; gf.out_f = out; gf.epi = 3;
  gemm_bt<<<dim3(32, 6), 256, 0, stream>>>(gf);
}

// Round 10
// 359.297 us; speedup vs baseline: 1.2103x; 1.0196x over previous
//
#include <hip/hip_runtime.h>
#include <hip/hip_bf16.h>
#include <stdint.h>

// SumThenRegRpeSelfAttention: B=4 T=1024 E=768 H=12 DH=64 P=65
// cast -> [stage1 GEMM qkv x6] -> sum-attn -> [k2v2 GEMM] -> reg-attn(+RPE) -> [out GEMM]
// Attention: swapped-QK^T (per-lane softmax), XOR-swizzled P buffer.
// GEMM: epilogue-through-LDS coalesced stores for head-major outputs.

#define DEV __device__ __forceinline__

using f32x4 = __attribute__((ext_vector_type(4))) float;
using s16x8 = __attribute__((ext_vector_type(8))) short;
using s16x4 = __attribute__((ext_vector_type(4))) short;
using i32x4 = __attribute__((ext_vector_type(4))) int;
using u32x2 = __attribute__((ext_vector_type(2))) unsigned int;
using fvec4 = __attribute__((ext_vector_type(4))) float;
using u16 = unsigned short;

static constexpr int KD = 768;            // inner K of every GEMM
static constexpr int PE = 4096 * 768;     // elems per projection tensor
static constexpr float QSCL = 0.18033688011112042f;  // 0.125 * log2(e)

DEV u16 f2bf(float f) {
  uint32_t u = __builtin_bit_cast(uint32_t, f);
  u += 0x7FFF + ((u >> 16) & 1);
  return (u16)(u >> 16);
}
DEV float bf2f(u16 h) { return __builtin_bit_cast(float, (uint32_t)h << 16); }
DEV unsigned int cvtpk(float a, float b) {  // lo=bf16(a), hi=bf16(b)
  unsigned int r;
  asm("v_cvt_pk_bf16_f32 %0, %1, %2" : "=v"(r) : "v"(a), "v"(b));
  return r;
}

DEV void gload16(const void* g, void* l) {
  __builtin_amdgcn_global_load_lds((const __attribute__((address_space(1))) void*)g,
                                   (__attribute__((address_space(3))) void*)l, 16, 0, 0);
}
DEV f32x4 mfma16(s16x8 a, s16x8 b, f32x4 c) {
  return __builtin_amdgcn_mfma_f32_16x16x32_bf16(a, b, c, 0, 0, 0);
}

// ---------------- cast f32 -> bf16 (14 jobs) ----------------
struct CastJobs {
  const float* src[14];
  u16* dst[14];
  int n[14];
};
__global__ __launch_bounds__(256) void cast_bf16_kernel(CastJobs J) {
  const int job = blockIdx.y;
  const int i = (blockIdx.x * 256 + threadIdx.x) * 8;
  if (i >= J.n[job]) return;
  const fvec4* s = (const fvec4*)(J.src[job] + i);
  fvec4 a = s[0], b = s[1];
  s16x8 o;
  o[0] = (short)f2bf(a[0]); o[1] = (short)f2bf(a[1]);
  o[2] = (short)f2bf(a[2]); o[3] = (short)f2bf(a[3]);
  o[4] = (short)f2bf(b[0]); o[5] = (short)f2bf(b[1]);
  o[6] = (short)f2bf(b[2]); o[7] = (short)f2bf(b[3]);
  *(s16x8*)(J.dst[job] + i) = o;
}

// ---------------- pack rel_pos0|rel_pos1 into u8 pairs ----------------
__global__ __launch_bounds__(256) void pack_rp_kernel(const int* rp0, const int* rp1, u16* outp) {
  const int i = (blockIdx.x * 256 + threadIdx.x) * 8;
  i32x4 a0 = *(const i32x4*)(rp0 + i), a1 = *(const i32x4*)(rp0 + i + 4);
  i32x4 b0 = *(const i32x4*)(rp1 + i), b1 = *(const i32x4*)(rp1 + i + 4);
  s16x8 o;
  o[0] = (short)(a0[0] | (b0[0] << 8));
  o[1] = (short)(a0[1] | (b0[1] << 8));
  o[2] = (short)(a0[2] | (b0[2] << 8));
  o[3] = (short)(a0[3] | (b0[3] << 8));
  o[4] = (short)(a1[0] | (b1[0] << 8));
  o[5] = (short)(a1[1] | (b1[1] << 8));
  o[6] = (short)(a1[2] | (b1[2] << 8));
  o[7] = (short)(a1[3] | (b1[3] << 8));
  *(s16x8*)(outp + i) = o;
}

// ---------------- generic GEMM: C = A(bf16, MxK) * W(bf16, NxK)^T ----------------
// epi: 0=stage1 (6 projections, head-major, V transposed), 1=k2v2, 2=rel table(s), 3=final f32
struct GemmP {
  const u16* A;
  const u16* Bw;
  const float* bias[6];
  u16* out_bf;
  float* out_f;
  const u16* A2;      // second table job (epi 2, blockIdx.z==1)
  const u16* Bw2;
  u16* out2;
  int epi;
};

__global__ __launch_bounds__(256) void gemm_bt(GemmP p) {
  __shared__ __align__(16) u16 smem[128 * 128];   // 32KB: A=first 16KB, B=next 16KB; epilogue C-tile
  u16* As = smem;
  u16* Bs = smem + 8192;
  const int tid = threadIdx.x;
  const int m0 = blockIdx.x * 128, n0 = blockIdx.y * 128;
  const int zz = blockIdx.z;
  const u16* Ag = (zz ? p.A2 : p.A) + (size_t)m0 * KD;
  const u16* Bg = (zz ? p.Bw2 : p.Bw) + (size_t)n0 * KD;
  const int lane = tid & 63, wid = tid >> 6;
  const int wm = (wid >> 1) * 64, wn = (wid & 1) * 64;
  const int lhi = lane >> 4, llo = lane & 15;

  uint ldso[4], srco[4];
#pragma unroll
  for (int j = 0; j < 4; ++j) {
    uint o = tid * 16 + j * 4096;
    uint row = o >> 7, kc = (o >> 4) & 7;
    ldso[j] = o;
    srco[j] = row * KD + ((kc ^ (row & 7)) << 3);
  }

  f32x4 acc[4][4] = {};

  for (int kt = 0; kt < 12; ++kt) {
    const int k0 = kt * 64;
#pragma unroll
    for (int j = 0; j < 4; ++j) gload16(Ag + srco[j] + k0, (char*)smem + ldso[j]);
#pragma unroll
    for (int j = 0; j < 4; ++j) gload16(Bg + srco[j] + k0, (char*)smem + 16384 + ldso[j]);
    __syncthreads();
#pragma unroll
    for (int kf = 0; kf < 2; ++kf) {
      s16x8 av[4], bv[4];
#pragma unroll
      for (int mf = 0; mf < 4; ++mf) {
        int r = wm + mf * 16 + llo;
        av[mf] = *(const s16x8*)&As[r * 64 + ((((kf << 2) | lhi) ^ (r & 7)) << 3)];
      }
#pragma unroll
      for (int nf = 0; nf < 4; ++nf) {
        int r = wn + nf * 16 + llo;
        bv[nf] = *(const s16x8*)&Bs[r * 64 + ((((kf << 2) | lhi) ^ (r & 7)) << 3)];
      }
#pragma unroll
      for (int mf = 0; mf < 4; ++mf)
#pragma unroll
        for (int nf = 0; nf < 4; ++nf)
          acc[mf][nf] = mfma16(av[mf], bv[nf], acc[mf][nf]);
    }
    __syncthreads();
  }

  const int epi = p.epi;
  const int proj0 = (epi <= 1) ? (n0 / 768) : 0;   // block-uniform (128-tile within one proj)
  const bool vlay_blk = (epi == 0 && (proj0 == 2 || proj0 == 5)) || (epi == 1 && proj0 == 1);

  if (epi <= 1 && !vlay_blk) {
    // ---- coalesced epilogue via LDS: head-major [bh][t][d] outputs ----
    const float scale = (epi == 0 && (proj0 == 0 || proj0 == 3)) ? QSCL : 1.0f;
#pragma unroll
    for (int nf = 0; nf < 4; ++nf) {
      const int nl = wn + nf * 16 + llo;                       // block-local col
      const float bias = p.bias[proj0][n0 + nl - proj0 * 768];
      const int nb = nl >> 3, ns = nl & 7;
#pragma unroll
      for (int mf = 0; mf < 4; ++mf) {
        const f32x4 c = acc[mf][nf];
        const int mb_ = wm + mf * 16 + lhi * 4;
#pragma unroll
        for (int r = 0; r < 4; ++r) {
          const int ml = mb_ + r;
          smem[ml * 128 + ((nb ^ (ml & 7)) << 3) + ns] = f2bf((c[r] + bias) * scale);
        }
      }
    }
    __syncthreads();
    const int j = tid & 7;                   // d-slice (8 u16)
    const int base = tid >> 3;               // 0..31
    const int seg = base & 1;                // which 64-col half (head)
    const int m_base = base >> 1;            // 0..15
    const int hh = (n0 + seg * 64 - proj0 * 768) >> 6;
#pragma unroll
    for (int w8 = 0; w8 < 8; ++w8) {
      const int ml = m_base + w8 * 16;
      const int bblk = seg * 8 + j;
      s16x8 v = *(const s16x8*)&smem[ml * 128 + ((bblk ^ (ml & 7)) << 3)];
      const int mg = m0 + ml;
      const int bi = mg >> 10, t = mg & 1023;
      const int bh = bi * 12 + hh;
      *(s16x8*)&p.out_bf[(size_t)proj0 * PE + ((size_t)(bh * 1024 + t)) * 64 + j * 8] = v;
    }
    return;
  }

  // ---- original epilogue paths: vlay (V, pre-transposed), rel tables, final f32 ----
#pragma unroll
  for (int nf = 0; nf < 4; ++nf) {
    const int n = n0 + wn + nf * 16 + llo;
    int proj = 0, n1 = n, hh, dd;
    float bias, scale = 1.0f;
    if (epi <= 1) {
      proj = proj0; n1 = n - proj * 768;
      hh = n1 >> 6; dd = n1 & 63;
      bias = p.bias[proj][n1];
    } else {
      hh = n >> 6; dd = n & 63;
      bias = p.bias[zz ? 1 : 0][n];
    }
#pragma unroll
    for (int mf = 0; mf < 4; ++mf) {
      f32x4 c = acc[mf][nf];
      const int mb = m0 + wm + mf * 16 + lhi * 4;
      if (epi == 3) {
#pragma unroll
        for (int r = 0; r < 4; ++r)
          p.out_f[(size_t)(mb + r) * 768 + n] = c[r] + bias;
      } else if (epi == 2) {
        u16* ob = zz ? p.out2 : p.out_bf;
#pragma unroll
        for (int r = 0; r < 4; ++r) {
          int m = mb + r;
          if (m < 80) ob[((size_t)hh * 80 + m) * 64 + dd] = f2bf(c[r] + bias);
        }
      } else {  // vlay: V stored transposed [bh][d][t]
        const int b = mb >> 10, t = mb & 1023;
        const int bh = b * 12 + hh;
        s16x4 o4;
        o4[0] = (short)f2bf((c[0] + bias) * scale);
        o4[1] = (short)f2bf((c[1] + bias) * scale);
        o4[2] = (short)f2bf((c[2] + bias) * scale);
        o4[3] = (short)f2bf((c[3] + bias) * scale);
        *(s16x4*)&p.out_bf[(size_t)proj * PE + ((size_t)(bh * 64 + dd)) * 1024 + t] = o4;
      }
    }
  }
}

// ---------------- sum-branch flash attention (swapped QK^T) ----------------
// 1-D grid 768 (XCD-swizzled), 256 thr, QB=64 (16 q-rows per wave), KB=64
__global__ __launch_bounds__(256) void sum_attn_kernel(const u16* Qs, const u16* Ks,
                                                       const u16* Vst, u16* sum_x) {
  __shared__ __align__(16) u16 kbuf[64 * 64];
  __shared__ __align__(16) u16 vbuf[64 * 64];
  __shared__ __align__(16) u16 pbuf[4][16 * 64];
  const int tid = threadIdx.x, lane = tid & 63, w = tid >> 6;
  const int lhi = lane >> 4, llo = lane & 15;
  const int bid = blockIdx.x;
  const int vid = (bid & 7) * 96 + (bid >> 3);
  const int qt = vid & 15, bh = vid >> 4;
  const int qbase = qt * 64 + w * 16;

  const u16* Qg = Qs + ((size_t)bh * 1024 + qbase + llo) * 64;
  s16x8 aq0 = *(const s16x8*)(Qg + lhi * 8);
  s16x8 aq1 = *(const s16x8*)(Qg + 32 + lhi * 8);

  f32x4 accO[4] = {};
  float mrun = -1e30f, lrun = 0.f;

  uint so[2], srow[2], sswz[2];
#pragma unroll
  for (int j = 0; j < 2; ++j) {
    uint o = tid * 16 + j * 4096;
    so[j] = o; srow[j] = o >> 7;
    sswz[j] = (((o >> 4) & 7) ^ (srow[j] & 7)) << 3;
  }
  const u16* Kg = Ks + (size_t)bh * 65536;
  const u16* Vg = Vst + (size_t)bh * 65536;

  for (int kt = 0; kt < 16; ++kt) {
#pragma unroll
    for (int j = 0; j < 2; ++j) {
      gload16(Kg + (size_t)kt * 4096 + srow[j] * 64 + sswz[j], (char*)kbuf + so[j]);
      gload16(Vg + (size_t)srow[j] * 1024 + kt * 64 + sswz[j], (char*)vbuf + so[j]);
    }
    __syncthreads();

    // scores: S[k=kc4*16+lhi*4+r][q=llo]  (swapped operands)
    f32x4 s[4];
    __builtin_amdgcn_s_setprio(1);
#pragma unroll
    for (int kc4 = 0; kc4 < 4; ++kc4) {
      f32x4 c = {};
#pragma unroll
      for (int kf = 0; kf < 2; ++kf) {
        int kr = kc4 * 16 + llo;
        s16x8 bk = *(const s16x8*)&kbuf[kr * 64 + ((((kf << 2) | lhi) ^ (kr & 7)) << 3)];
        c = mfma16(bk, kf ? aq1 : aq0, c);
      }
      s[kc4] = c;
    }
    __builtin_amdgcn_s_setprio(0);

    // per-lane softmax state (one q-row per lane)
    float smx = s[0][0];
#pragma unroll
    for (int kc4 = 0; kc4 < 4; ++kc4)
#pragma unroll
      for (int r = 0; r < 4; ++r) smx = fmaxf(smx, s[kc4][r]);
    if (!__all(smx <= mrun + 8.0f)) {
      float mall = fmaxf(smx, __shfl_xor(smx, 16, 64));
      mall = fmaxf(mall, __shfl_xor(mall, 32, 64));
      float mn = fmaxf(mrun, mall);
      float corr = exp2f(mrun - mn);
      mrun = mn;
      lrun *= corr;
      float cf[4];
#pragma unroll
      for (int r = 0; r < 4; ++r) cf[r] = __shfl(corr, lhi * 4 + r, 64);
#pragma unroll
      for (int dc = 0; dc < 4; ++dc)
#pragma unroll
        for (int r = 0; r < 4; ++r) accO[dc][r] *= cf[r];
    }
    float ls = 0.f;
#pragma unroll
    for (int kc4 = 0; kc4 < 4; ++kc4) {
      float p0 = exp2f(s[kc4][0] - mrun), p1 = exp2f(s[kc4][1] - mrun);
      float p2 = exp2f(s[kc4][2] - mrun), p3 = exp2f(s[kc4][3] - mrun);
      ls += (p0 + p1) + (p2 + p3);
      u32x2 pk; pk[0] = cvtpk(p0, p1); pk[1] = cvtpk(p2, p3);
      const int kb = (kc4 << 1) | (lhi >> 1);
      *(u32x2*)&pbuf[w][llo * 64 + ((kb ^ (llo & 7)) << 3) + ((lhi & 1) << 2)] = pk;
    }
    lrun += ls;

    asm volatile("s_waitcnt lgkmcnt(0)" ::: "memory");
    __builtin_amdgcn_sched_barrier(0);

    __builtin_amdgcn_s_setprio(1);
#pragma unroll
    for (int kf = 0; kf < 2; ++kf) {
      const int kb = (kf << 2) | lhi;
      s16x8 ap = *(const s16x8*)&pbuf[w][llo * 64 + ((kb ^ (llo & 7)) << 3)];
#pragma unroll
      for (int dc = 0; dc < 4; ++dc) {
        int dr = dc * 16 + llo;
        s16x8 bv = *(const s16x8*)&vbuf[dr * 64 + ((((kf << 2) | lhi) ^ (dr & 7)) << 3)];
        accO[dc] = mfma16(ap, bv, accO[dc]);
      }
    }
    __builtin_amdgcn_s_setprio(0);
    __syncthreads();
  }

  lrun += __shfl_xor(lrun, 16, 64);
  lrun += __shfl_xor(lrun, 32, 64);
  float linv[4];
#pragma unroll
  for (int r = 0; r < 4; ++r) linv[r] = 1.0f / __shfl(lrun, lhi * 4 + r, 64);

  const int b = bh / 12, hh = bh - b * 12;
#pragma unroll
  for (int dc = 0; dc < 4; ++dc)
#pragma unroll
    for (int r = 0; r < 4; ++r) {
      int q = qbase + lhi * 4 + r;
      sum_x[((size_t)b * 1024 + q) * 768 + hh * 64 + dc * 16 + llo] = f2bf(accO[dc][r] * linv[r]);
    }
}

// ---------------- reg-branch flash attention with RPE gather (swapped QK^T) ----------------
__global__ __launch_bounds__(256) void reg_attn_kernel(
    const u16* Qr, const u16* Kr, const u16* Vrt,
    const u16* K2, const u16* V2t,
    const u16* tab0, const u16* tab1,
    const u16* rpk, u16* attn_out) {
  __shared__ __align__(16) u16 kbuf[64 * 64];
  __shared__ __align__(16) u16 vbuf[64 * 64];
  __shared__ __align__(16) u16 tsb0[64 * 80];
  __shared__ __align__(16) u16 tsb1[64 * 80];
  __shared__ __align__(16) u16 pbuf[4][16 * 64];
  const int tid = threadIdx.x, lane = tid & 63, w = tid >> 6;
  const int lhi = lane >> 4, llo = lane & 15;
  const int bid = blockIdx.x;
  const int vid = (bid & 7) * 96 + (bid >> 3);
  const int qt = vid & 15, bh = vid >> 4;
  const int b = bh / 12, hh = bh - b * 12;
  const int qbase = qt * 64 + w * 16;
  const int qloc = w * 16 + llo;       // this lane's q-row (block-local) in score layout

  const u16* Qg = Qr + ((size_t)bh * 1024 + qbase + llo) * 64;
  s16x8 aq0 = *(const s16x8*)(Qg + lhi * 8);
  s16x8 aq1 = *(const s16x8*)(Qg + 32 + lhi * 8);

  // ts[p][q] = table[p] . q  (swapped: q in cols). Write packed pairs.
#pragma unroll
  for (int tt = 0; tt < 2; ++tt) {
    const u16* tb = tt ? tab1 : tab0;
    u16* dst = tt ? tsb1 : tsb0;
#pragma unroll
    for (int pf = 0; pf < 5; ++pf) {
      f32x4 c = {};
#pragma unroll
      for (int kf = 0; kf < 2; ++kf) {
        s16x8 bt = *(const s16x8*)(tb + ((size_t)hh * 80 + pf * 16 + llo) * 64 + kf * 32 + lhi * 8);
        c = mfma16(bt, kf ? aq1 : aq0, c);
      }
      u32x2 pk; pk[0] = cvtpk(c[0], c[1]); pk[1] = cvtpk(c[2], c[3]);
      *(u32x2*)&dst[(w * 16 + llo) * 80 + pf * 16 + lhi * 4] = pk;
    }
  }
  __syncthreads();

  f32x4 accO[4] = {};
  float mrun = -1e30f, lrun = 0.f;

  uint so[2], srow[2], sswz[2];
#pragma unroll
  for (int j = 0; j < 2; ++j) {
    uint o = tid * 16 + j * 4096;
    so[j] = o; srow[j] = o >> 7;
    sswz[j] = (((o >> 4) & 7) ^ (srow[j] & 7)) << 3;
  }
  const u16* KgA = Kr + (size_t)bh * 65536;
  const u16* KgB = K2 + (size_t)bh * 65536;
  const u16* VgA = Vrt + (size_t)bh * 65536;
  const u16* VgB = V2t + (size_t)bh * 65536;

  auto tile = [&](const u16* Kg, const u16* Vg, int kk, bool gather) {
#pragma unroll
    for (int j = 0; j < 2; ++j) {
      gload16(Kg + (size_t)kk * 4096 + srow[j] * 64 + sswz[j], (char*)kbuf + so[j]);
      gload16(Vg + (size_t)srow[j] * 1024 + kk * 64 + sswz[j], (char*)vbuf + so[j]);
    }
    // vector-load gather indices before the barrier (latency hides under vmcnt drain)
    s16x4 pp4[4];
    if (gather) {
#pragma unroll
      for (int kc4 = 0; kc4 < 4; ++kc4)
        pp4[kc4] = *(const s16x4*)&rpk[(size_t)(qbase + llo) * 1024 + kk * 64 + kc4 * 16 + lhi * 4];
    }
    __syncthreads();

    f32x4 s[4];
    __builtin_amdgcn_s_setprio(1);
#pragma unroll
    for (int kc4 = 0; kc4 < 4; ++kc4) {
      f32x4 c = {};
#pragma unroll
      for (int kf = 0; kf < 2; ++kf) {
        int kr = kc4 * 16 + llo;
        s16x8 bk = *(const s16x8*)&kbuf[kr * 64 + ((((kf << 2) | lhi) ^ (kr & 7)) << 3)];
        c = mfma16(bk, kf ? aq1 : aq0, c);
      }
      s[kc4] = c;
    }
    __builtin_amdgcn_s_setprio(0);

    if (gather) {
#pragma unroll
      for (int kc4 = 0; kc4 < 4; ++kc4)
#pragma unroll
        for (int r = 0; r < 4; ++r) {
          int v = (u16)pp4[kc4][r];
          s[kc4][r] += bf2f(tsb0[qloc * 80 + (v & 255)]) + bf2f(tsb1[qloc * 80 + (v >> 8)]);
        }
    }

    float smx = s[0][0];
#pragma unroll
    for (int kc4 = 0; kc4 < 4; ++kc4)
#pragma unroll
      for (int r = 0; r < 4; ++r) smx = fmaxf(smx, s[kc4][r]);
    if (!__all(smx <= mrun + 8.0f)) {
      float mall = fmaxf(smx, __shfl_xor(smx, 16, 64));
      mall = fmaxf(mall, __shfl_xor(mall, 32, 64));
      float mn = fmaxf(mrun, mall);
      float corr = exp2f(mrun - mn);
      mrun = mn;
      lrun *= corr;
      float cf[4];
#pragma unroll
      for (int r = 0; r < 4; ++r) cf[r] = __shfl(corr, lhi * 4 + r, 64);
#pragma unroll
      for (int dc = 0; dc < 4; ++dc)
#pragma unroll
        for (int r = 0; r < 4; ++r) accO[dc][r] *= cf[r];
    }
    float ls = 0.f;
#pragma unroll
    for (int kc4 = 0; kc4 < 4; ++kc4) {
      float p0 = exp2f(s[kc4][0] - mrun), p1 = exp2f(s[kc4][1] - mrun);
      float p2 = exp2f(s[kc4][2] - mrun), p3 = exp2f(s[kc4][3] - mrun);
      ls += (p0 + p1) + (p2 + p3);
      u32x2 pk; pk[0] = cvtpk(p0, p1); pk[1] = cvtpk(p2, p3);
      const int kb = (kc4 << 1) | (lhi >> 1);
      *(u32x2*)&pbuf[w][llo * 64 + ((kb ^ (llo & 7)) << 3) + ((lhi & 1) << 2)] = pk;
    }
    lrun += ls;

    asm volatile("s_waitcnt lgkmcnt(0)" ::: "memory");
    __builtin_amdgcn_sched_barrier(0);

    __builtin_amdgcn_s_setprio(1);
#pragma unroll
    for (int kf = 0; kf < 2; ++kf) {
      const int kb = (kf << 2) | lhi;
      s16x8 ap = *(const s16x8*)&pbuf[w][llo * 64 + ((kb ^ (llo & 7)) << 3)];
#pragma unroll
      for (int dc = 0; dc < 4; ++dc) {
        int dr = dc * 16 + llo;
        s16x8 bv = *(const s16x8*)&vbuf[dr * 64 + ((((kf << 2) | lhi) ^ (dr & 7)) << 3)];
        accO[dc] = mfma16(ap, bv, accO[dc]);
      }
    }
    __builtin_amdgcn_s_setprio(0);
    __syncthreads();
  };

  for (int kt = 0; kt < 16; ++kt) tile(KgA, VgA, kt, true);    // reg keys + RPE
  for (int kt = 0; kt < 16; ++kt) tile(KgB, VgB, kt, false);   // sum keys

  lrun += __shfl_xor(lrun, 16, 64);
  lrun += __shfl_xor(lrun, 32, 64);
  float linv[4];
#pragma unroll
  for (int r = 0; r < 4; ++r) linv[r] = 1.0f / __shfl(lrun, lhi * 4 + r, 64);

#pragma unroll
  for (int dc = 0; dc < 4; ++dc)
#pragma unroll
    for (int r = 0; r < 4; ++r) {
      int q = qbase + lhi * 4 + r;
      attn_out[((size_t)b * 1024 + q) * 768 + hh * 64 + dc * 16 + llo] = f2bf(accO[dc][r] * linv[r]);
    }
}

// ---------------- launch ----------------
extern "C" void kernel_launch(void* const* d_in, const int* in_sizes, int n_in,
                              void* d_out, int out_size, void* d_ws, size_t ws_size,
                              hipStream_t stream) {
  (void)in_sizes; (void)n_in; (void)out_size; (void)ws_size;
  const float* x     = (const float*)d_in[0];
  const int*   rp0   = (const int*)d_in[1];
  const int*   rp1   = (const int*)d_in[2];
  const float* re0   = (const float*)d_in[3];
  const float* re1   = (const float*)d_in[4];
  const float* Wq_r  = (const float*)d_in[5];  const float* bq_r = (const float*)d_in[6];
  const float* Wk_r  = (const float*)d_in[7];  const float* bk_r = (const float*)d_in[8];
  const float* Wv_r  = (const float*)d_in[9];  const float* bv_r = (const float*)d_in[10];
  const float* Wq_s  = (const float*)d_in[11]; const float* bq_s = (const float*)d_in[12];
  const float* Wk_s  = (const float*)d_in[13]; const float* bk_s = (const float*)d_in[14];
  const float* Wv_s  = (const float*)d_in[15]; const float* bv_s = (const float*)d_in[16];
  const float* Wk2   = (const float*)d_in[17]; const float* bk2  = (const float*)d_in[18];
  const float* Wv2   = (const float*)d_in[19]; const float* bv2  = (const float*)d_in[20];
  const float* Wrel0 = (const float*)d_in[21]; const float* brel0 = (const float*)d_in[22];
  const float* Wrel1 = (const float*)d_in[23]; const float* brel1 = (const float*)d_in[24];
  const float* Wo    = (const float*)d_in[25]; const float* bo   = (const float*)d_in[26];
  float* out = (float*)d_out;

  char* wp = (char*)d_ws;
  auto carve = [&](size_t bytes) {
    char* r = wp;
    wp += (bytes + 255) & ~(size_t)255;
    return r;
  };
  u16* xb     = (u16*)carve((size_t)PE * 2);
  u16* Wcat1  = (u16*)carve((size_t)4608 * 768 * 2);
  u16* Wcat2  = (u16*)carve((size_t)1536 * 768 * 2);
  u16* Wrel0b = (u16*)carve((size_t)768 * 768 * 2);
  u16* Wrel1b = (u16*)carve((size_t)768 * 768 * 2);
  u16* Wob    = (u16*)carve((size_t)768 * 768 * 2);
  u16* relA0  = (u16*)carve((size_t)128 * 768 * 2);
  u16* relA1  = (u16*)carve((size_t)128 * 768 * 2);
  u16* qkv    = (u16*)carve((size_t)6 * PE * 2);   // Qr,Kr,Vrt,Qs,Ks,Vst
  u16* k2v2   = (u16*)carve((size_t)2 * PE * 2);   // K2, V2t
  u16* tb0    = (u16*)carve((size_t)12 * 80 * 64 * 2);
  u16* tb1    = (u16*)carve((size_t)12 * 80 * 64 * 2);
  u16* rpk    = (u16*)carve((size_t)1024 * 1024 * 2);
  u16* sumx   = (u16*)carve((size_t)PE * 2);
  u16* aout   = (u16*)carve((size_t)PE * 2);

  const int wn_ = 768 * 768;
  CastJobs J;
  const float* srcs[14] = {x, Wq_r, Wk_r, Wv_r, Wq_s, Wk_s, Wv_s, Wk2, Wv2, Wrel0, Wrel1, Wo, re0, re1};
  u16* dsts[14] = {xb, Wcat1, Wcat1 + wn_, Wcat1 + 2 * wn_, Wcat1 + 3 * wn_, Wcat1 + 4 * wn_,
                   Wcat1 + 5 * wn_, Wcat2, Wcat2 + wn_, Wrel0b, Wrel1b, Wob, relA0, relA1};
  int ns[14] = {PE, wn_, wn_, wn_, wn_, wn_, wn_, wn_, wn_, wn_, wn_, wn_, 65 * 768, 65 * 768};
  for (int i = 0; i < 14; ++i) { J.src[i] = srcs[i]; J.dst[i] = dsts[i]; J.n[i] = ns[i]; }
  cast_bf16_kernel<<<dim3(1536, 14), 256, 0, stream>>>(J);

  pack_rp_kernel<<<dim3(512), 256, 0, stream>>>(rp0, rp1, rpk);

  GemmP g1{};
  g1.A = xb; g1.Bw = Wcat1;
  g1.bias[0] = bq_r; g1.bias[1] = bk_r; g1.bias[2] = bv_r;
  g1.bias[3] = bq_s; g1.bias[4] = bk_s; g1.bias[5] = bv_s;
  g1.out_bf = qkv; g1.epi = 0;
  gemm_bt<<<dim3(32, 36), 256, 0, stream>>>(g1);

  GemmP gt{};
  gt.A = relA0; gt.Bw = Wrel0b; gt.bias[0] = brel0; gt.out_bf = tb0;
  gt.A2 = relA1; gt.Bw2 = Wrel1b; gt.bias[1] = brel1; gt.out2 = tb1;
  gt.epi = 2;
  gemm_bt<<<dim3(1, 6, 2), 256, 0, stream>>>(gt);

  sum_attn_kernel<<<dim3(768), 256, 0, stream>>>(qkv + (size_t)3 * PE, qkv + (size_t)4 * PE,
                                                 qkv + (size_t)5 * PE, sumx);

  GemmP g2{};
  g2.A = sumx; g2.Bw = Wcat2; g2.bias[0] = bk2; g2.bias[1] = bv2;
  g2.out_bf = k2v2; g2.epi = 1;
  gemm_bt<<<dim3(32, 12), 256, 0, stream>>>(g2);

  reg_attn_kernel<<<dim3(768), 256, 0, stream>>>(qkv, qkv + (size_t)PE, qkv + (size_t)2 * PE,
                                                 k2v2, k2v2 + (size_t)PE, tb0, tb1, rpk, aout);

  GemmP gf{};
  gf.A = aout; gf.Bw = Wob; gf.bias[0] = bo; gf.out_f = out; gf.epi = 3;
  gemm_bt<<<dim3(32, 6), 256, 0, stream>>>(gf);
}